// Round 5
// baseline (4853.724 us; speedup 1.0000x reference)
//
#include <hip/hip_runtime.h>
#include <stdint.h>

#define B_TRAJ  4096
#define H_DIM   100
#define T_STEPS 100
#define ROWS    16
#define NBLK    256
#define THREADS 1024

typedef float    f32x4  __attribute__((ext_vector_type(4)));
typedef __bf16   bf16x8 __attribute__((ext_vector_type(8)));
typedef uint16_t u16x8  __attribute__((ext_vector_type(8)));

// ---- packed-weight layout in d_ws (u16/bf16 elements) ----
// within a pack: idx = (kt*N + n)*32 + kk ; kk = g*8 + e maps k = kt*32+kk
#define OFF_P0F  0        // [4][256][32]  W0[n][k]  (K pad 128)
#define OFF_P1F  32768    // [8][256][32]  W1[n][k]
#define OFF_P2F  98304
#define OFF_P3F  163840
#define OFF_P1B  229376   // [8][256][32]  W1[k][n]
#define OFF_P2B  294912
#define OFF_P3B  360448
#define OFF_P0B  425984   // [8][128][32]  W0[k][1+n] (N pad 128)
#define OFF_W4P  458752   // [256] bf16 W4 linear
#define OFF_KEYS 459008   // 200 x u32 (as 400 u16 slots)
#define PACK_TOTAL 459008
#define PACK_GRID ((PACK_TOTAL + 255) / 256)

__device__ __forceinline__ uint16_t f2bf(float f) {
  uint32_t u = __float_as_uint(f);
  uint32_t r = u + 0x7FFFu + ((u >> 16) & 1u);   // RNE
  return (uint16_t)(r >> 16);
}
__device__ __forceinline__ float bf2f(uint16_t u) {
  return __uint_as_float(((uint32_t)u) << 16);
}
__device__ __forceinline__ uint32_t rotl32(uint32_t v, int d) {
  return (v << d) | (v >> (32 - d));
}

// JAX Threefry-2x32, 20 rounds, exact key schedule.
__device__ __forceinline__ void threefry2x32(uint32_t k0, uint32_t k1,
                                             uint32_t x0, uint32_t x1,
                                             uint32_t& o0, uint32_t& o1) {
  const uint32_t k2 = k0 ^ k1 ^ 0x1BD11BDAu;
  x0 += k0; x1 += k1;
  x0 += x1; x1 = rotl32(x1, 13); x1 ^= x0;
  x0 += x1; x1 = rotl32(x1, 15); x1 ^= x0;
  x0 += x1; x1 = rotl32(x1, 26); x1 ^= x0;
  x0 += x1; x1 = rotl32(x1,  6); x1 ^= x0;
  x0 += k1; x1 += k2 + 1u;
  x0 += x1; x1 = rotl32(x1, 17); x1 ^= x0;
  x0 += x1; x1 = rotl32(x1, 29); x1 ^= x0;
  x0 += x1; x1 = rotl32(x1, 16); x1 ^= x0;
  x0 += x1; x1 = rotl32(x1, 24); x1 ^= x0;
  x0 += k2; x1 += k0 + 2u;
  x0 += x1; x1 = rotl32(x1, 13); x1 ^= x0;
  x0 += x1; x1 = rotl32(x1, 15); x1 ^= x0;
  x0 += x1; x1 = rotl32(x1, 26); x1 ^= x0;
  x0 += x1; x1 = rotl32(x1,  6); x1 ^= x0;
  x0 += k0; x1 += k1 + 3u;
  x0 += x1; x1 = rotl32(x1, 17); x1 ^= x0;
  x0 += x1; x1 = rotl32(x1, 29); x1 ^= x0;
  x0 += x1; x1 = rotl32(x1, 16); x1 ^= x0;
  x0 += x1; x1 = rotl32(x1, 24); x1 ^= x0;
  x0 += k1; x1 += k2 + 4u;
  x0 += x1; x1 = rotl32(x1, 13); x1 ^= x0;
  x0 += x1; x1 = rotl32(x1, 15); x1 ^= x0;
  x0 += x1; x1 = rotl32(x1, 26); x1 ^= x0;
  x0 += x1; x1 = rotl32(x1,  6); x1 ^= x0;
  x0 += k2; x1 += k0 + 5u;
  o0 = x0; o1 = x1;
}

// XLA ErfInv32 (Giles)
__device__ __forceinline__ float erfinv_f32(float x) {
  float w = -log1pf(-x * x);
  float p;
  if (w < 5.0f) {
    w = w - 2.5f;
    p = 2.81022636e-08f;
    p = fmaf(p, w, 3.43273939e-07f);
    p = fmaf(p, w, -3.5233877e-06f);
    p = fmaf(p, w, -4.39150654e-06f);
    p = fmaf(p, w, 0.00021858087f);
    p = fmaf(p, w, -0.00125372503f);
    p = fmaf(p, w, -0.00417768164f);
    p = fmaf(p, w, 0.246640727f);
    p = fmaf(p, w, 1.50140941f);
  } else {
    w = sqrtf(w) - 3.0f;
    p = -0.000200214257f;
    p = fmaf(p, w, 0.000100950558f);
    p = fmaf(p, w, 0.00134934322f);
    p = fmaf(p, w, -0.00367342844f);
    p = fmaf(p, w, 0.00573950773f);
    p = fmaf(p, w, -0.0076224613f);
    p = fmaf(p, w, 0.00943887047f);
    p = fmaf(p, w, 1.00167406f);
    p = fmaf(p, w, 2.83297682f);
  }
  return p * x;
}

// ---------------- weight packing + key chain (once per launch) ----------------
__global__ __launch_bounds__(256) void pack_kernel(
    const float* __restrict__ W0, const float* __restrict__ W1,
    const float* __restrict__ W2, const float* __restrict__ W3,
    const float* __restrict__ W4, uint16_t* __restrict__ P) {
  const int i = blockIdx.x * 256 + threadIdx.x;
  if (i == 0) {  // serial key chain: key(42), per step use child0, carry child1
    uint32_t* K = (uint32_t*)(P + OFF_KEYS);
    uint32_t c0 = 0u, c1 = 42u;
    for (int s = 0; s < T_STEPS; ++s) {
      uint32_t a0_, a1_, n0, n1;
      threefry2x32(c0, c1, 0u, 0u, a0_, a1_);
      threefry2x32(c0, c1, 0u, 1u, n0, n1);
      K[2 * s] = a0_; K[2 * s + 1] = a1_;
      c0 = n0; c1 = n1;
    }
  }
  if (i >= PACK_TOTAL) return;
  float v;
  if (i < OFF_P1F) {                 // P0F
    int e = i - OFF_P0F;
    int kk = e & 31, n = (e >> 5) & 255, kt = e >> 13;
    int k = kt * 32 + kk;
    v = (k < 101) ? W0[n * 101 + k] : 0.0f;
  } else if (i < OFF_P2F) {          // P1F
    int e = i - OFF_P1F;
    int kk = e & 31, n = (e >> 5) & 255, kt = e >> 13;
    v = W1[n * 256 + kt * 32 + kk];
  } else if (i < OFF_P3F) {          // P2F
    int e = i - OFF_P2F;
    int kk = e & 31, n = (e >> 5) & 255, kt = e >> 13;
    v = W2[n * 256 + kt * 32 + kk];
  } else if (i < OFF_P1B) {          // P3F
    int e = i - OFF_P3F;
    int kk = e & 31, n = (e >> 5) & 255, kt = e >> 13;
    v = W3[n * 256 + kt * 32 + kk];
  } else if (i < OFF_P2B) {          // P1B
    int e = i - OFF_P1B;
    int kk = e & 31, n = (e >> 5) & 255, kt = e >> 13;
    v = W1[(kt * 32 + kk) * 256 + n];
  } else if (i < OFF_P3B) {          // P2B
    int e = i - OFF_P2B;
    int kk = e & 31, n = (e >> 5) & 255, kt = e >> 13;
    v = W2[(kt * 32 + kk) * 256 + n];
  } else if (i < OFF_P0B) {          // P3B
    int e = i - OFF_P3B;
    int kk = e & 31, n = (e >> 5) & 255, kt = e >> 13;
    v = W3[(kt * 32 + kk) * 256 + n];
  } else if (i < OFF_W4P) {          // P0B
    int e = i - OFF_P0B;
    int kk = e & 31, n = (e >> 5) & 127, kt = e >> 12;
    int k = kt * 32 + kk;
    v = (n < 100) ? W0[k * 101 + 1 + n] : 0.0f;
  } else {                           // W4P
    v = W4[i - OFF_W4P];
  }
  P[i] = f2bf(v);
}

// ---------------- LDS ----------------
struct SmemT {
  uint16_t actI[ROWS][136];   // MLP input, K padded to 128
  uint16_t act1[ROWS][264];
  uint16_t act2[ROWS][264];
  uint16_t act3[ROWS][264];
  uint16_t act4[ROWS][264];
  uint16_t dpA[ROWS][264];
  uint16_t dpB[ROWS][264];
  float x_s[ROWS * H_DIM];
  float z_s[ROWS * H_DIM];
  float dw_s[ROWS * H_DIM];
  float y_s[ROWS];
  uint32_t keyA[T_STEPS], keyB[T_STEPS];
};

// ---------------- fragment load helpers ----------------
template<int KT, int STRIDE_EL>
__device__ __forceinline__ void load_frags(bf16x8 (&f)[8],
                                           const uint16_t* __restrict__ Pm,
                                           uint32_t voff) {
#pragma unroll
  for (int kt = 0; kt < KT; ++kt)
    f[kt] = *reinterpret_cast<const bf16x8*>(Pm + kt * STRIDE_EL + voff);
}

// ---------------- GEMM phase bodies (MFMA 16x16x32 bf16) ----------------
// D[r][c]: r=(lane>>4)*4+reg, c=lane&15 (m89).  A[r][kslot]: r=lane&15.
// kslot=(g,e) packing identical on A and B, so HW k-permutation cancels.

template<int INS>
__device__ __forceinline__ void fwd_do(const uint16_t (*in)[INS],
                                       const bf16x8 (&f)[8],
                                       const float* __restrict__ bias,
                                       uint16_t (*outb)[264],
                                       int row16, int g, int c) {
  const float bv = bias[c];
  f32x4 acc = {bv, bv, bv, bv};
#pragma unroll
  for (int kt = 0; kt < 8; ++kt) {
    bf16x8 a = *reinterpret_cast<const bf16x8*>(&in[row16][kt * 32 + g * 8]);
    acc = __builtin_amdgcn_mfma_f32_16x16x32_bf16(a, f[kt], acc, 0, 0, 0);
  }
#pragma unroll
  for (int reg = 0; reg < 4; ++reg)
    outb[g * 4 + reg][c] = f2bf(fmaxf(acc[reg], 0.0f));
}

__device__ __forceinline__ void bwd_do(const uint16_t (*in)[264],
                                       const bf16x8 (&f)[8],
                                       const uint16_t (*mact)[264],
                                       uint16_t (*outb)[264],
                                       int row16, int g, int c) {
  f32x4 acc = {0.f, 0.f, 0.f, 0.f};
#pragma unroll
  for (int kt = 0; kt < 8; ++kt) {
    bf16x8 a = *reinterpret_cast<const bf16x8*>(&in[row16][kt * 32 + g * 8]);
    acc = __builtin_amdgcn_mfma_f32_16x16x32_bf16(a, f[kt], acc, 0, 0, 0);
  }
#pragma unroll
  for (int reg = 0; reg < 4; ++reg) {
    const int r = g * 4 + reg;
    outb[r][c] = mact[r][c] ? f2bf(acc[reg]) : (uint16_t)0;
  }
}

// ---------------- main kernel ----------------
__global__ __launch_bounds__(THREADS, 4) void fbsde_kernel(
    const float* __restrict__ x0, const float* __restrict__ t0p,
    const float* __restrict__ dtp,
    const float* __restrict__ b0, const float* __restrict__ b1,
    const float* __restrict__ b2, const float* __restrict__ b3,
    const float* __restrict__ W4, const float* __restrict__ b4,
    const uint16_t* __restrict__ P, float* __restrict__ out) {
  __shared__ __align__(16) SmemT sm;

  const int tid = threadIdx.x;
  const int wave = tid >> 6, lane = tid & 63;
  const int row16 = lane & 15, g = lane >> 4;
  const int c = row16 + 16 * wave;
  const uint32_t voff = (uint32_t)(c * 32 + g * 8);   // fragment element offset
  const int blk = blockIdx.x;
  const int row0 = blk * ROWS;

  // strict ping-pong fragment buffers (the ONLY long-lived VGPR arrays)
  bf16x8 fA[8], fB[8];

  // ---- init ----
  if (tid < T_STEPS) {
    const uint32_t* K = (const uint32_t*)(P + OFF_KEYS);
    sm.keyA[tid] = K[2 * tid];
    sm.keyB[tid] = K[2 * tid + 1];
  }
  for (int e = tid; e < ROWS * H_DIM; e += THREADS)
    sm.x_s[e] = x0[row0 * H_DIM + e];
  for (int e = tid; e < ROWS * 136; e += THREADS) {
    const int r = e / 136, cc = e - r * 136;
    uint16_t v = 0;
    if (cc >= 1 && cc <= H_DIM) v = f2bf(x0[(row0 + r) * H_DIM + cc - 1]);
    sm.actI[r][cc] = v;   // cc==0 -> t=0.0 -> bf16 0
  }
  load_frags<4, 8192>(fB, P + OFF_P0F, voff);   // first eval's P0F
  const float t0v = t0p[0];
  const float dtv = dtp[0];
  const float sqdt = sqrtf(dtv);
  __syncthreads();

  float* const out_xfin = out;                                  // (B,H)
  float* const out_yfin = out + 409600;                         // (B,1)
  float* const out_zfin = out + 413696;                         // (B,H)
  float* const out_xs   = out + 823296;                         // (T,B,H)
  float* const out_yt   = out + 823296 + 40960000;              // (T,B,1)
  float* const out_ys   = out + 823296 + 40960000 + 409600;     // (T,B,1)

  // ---- one MLP fwd+VJP eval, ping-pong prefetch across all 8 phases ----
  // entry: fB = this eval's P0F. exit: fB = next eval's P0F.
  auto mlp_eval = [&](float* ys_out, int next_s) {
    // P0: use fB (P0F), prefetch P1F -> fA
    load_frags<8, 8192>(fA, P + OFF_P1F, voff);
    __builtin_amdgcn_sched_barrier(0);
    {
      const float bv = b0[c];
      f32x4 acc = {bv, bv, bv, bv};
#pragma unroll
      for (int kt = 0; kt < 4; ++kt) {
        bf16x8 a = *reinterpret_cast<const bf16x8*>(&sm.actI[row16][kt * 32 + g * 8]);
        acc = __builtin_amdgcn_mfma_f32_16x16x32_bf16(a, fB[kt], acc, 0, 0, 0);
      }
#pragma unroll
      for (int reg = 0; reg < 4; ++reg)
        sm.act1[g * 4 + reg][c] = f2bf(fmaxf(acc[reg], 0.0f));
    }
    __syncthreads();

    // P1: use fA (P1F), prefetch P2F -> fB
    load_frags<8, 8192>(fB, P + OFF_P2F, voff);
    __builtin_amdgcn_sched_barrier(0);
    fwd_do<264>(sm.act1, fA, b1, sm.act2, row16, g, c);
    __syncthreads();

    // P2: use fB (P2F), prefetch P3F -> fA
    load_frags<8, 8192>(fA, P + OFF_P3F, voff);
    __builtin_amdgcn_sched_barrier(0);
    fwd_do<264>(sm.act2, fB, b2, sm.act3, row16, g, c);
    __syncthreads();

    // P3: use fA (P3F), prefetch P3B -> fB
    load_frags<8, 8192>(fB, P + OFF_P3B, voff);
    __builtin_amdgcn_sched_barrier(0);
    fwd_do<264>(sm.act3, fA, b3, sm.act4, row16, g, c);
    __syncthreads();

    // P4: use fB (P3B): y-reduce + bwd3 (dp4 built on the fly);
    //     prefetch P2B -> fA
    load_frags<8, 8192>(fA, P + OFF_P2B, voff);
    __builtin_amdgcn_sched_barrier(0);
    {
      float s = 0.0f;
#pragma unroll
      for (int m = 0; m < 4; ++m) {
        const int j = lane + (m << 6);
        s += bf2f(sm.act4[wave][j]) * W4[j];
      }
#pragma unroll
      for (int off = 32; off >= 1; off >>= 1) s += __shfl_xor(s, off, 64);
      if (lane == 0) {
        const float yv = s + b4[0];
        sm.y_s[wave] = yv;
        if (ys_out) ys_out[row0 + wave] = yv;
      }
      const uint16_t* W4P = P + OFF_W4P;
      f32x4 acc = {0.f, 0.f, 0.f, 0.f};
#pragma unroll
      for (int kt = 0; kt < 8; ++kt) {
        u16x8 au = *reinterpret_cast<const u16x8*>(&sm.act4[row16][kt * 32 + g * 8]);
        u16x8 wu = *reinterpret_cast<const u16x8*>(&W4P[kt * 32 + g * 8]);
        u16x8 sel;
#pragma unroll
        for (int e = 0; e < 8; ++e) sel[e] = au[e] ? wu[e] : (uint16_t)0;
        acc = __builtin_amdgcn_mfma_f32_16x16x32_bf16(
            __builtin_bit_cast(bf16x8, sel), fB[kt], acc, 0, 0, 0);
      }
#pragma unroll
      for (int reg = 0; reg < 4; ++reg) {
        const int r = g * 4 + reg;
        sm.dpA[r][c] = sm.act3[r][c] ? f2bf(acc[reg]) : (uint16_t)0;
      }
    }
    __syncthreads();

    // P5: use fA (P2B), prefetch P1B -> fB
    load_frags<8, 8192>(fB, P + OFF_P1B, voff);
    __builtin_amdgcn_sched_barrier(0);
    bwd_do(sm.dpA, fA, sm.act2, sm.dpB, row16, g, c);
    __syncthreads();

    // P6: use fB (P1B), prefetch P0B -> fA (waves 0-7 only; c<128 valid)
    if (wave < 8) load_frags<8, 4096>(fA, P + OFF_P0B, voff);
    __builtin_amdgcn_sched_barrier(0);
    bwd_do(sm.dpB, fB, sm.act1, sm.dpA, row16, g, c);
    __syncthreads();

    // P7: use fA (P0B) for bwd0 on waves 0-7; waves 8-15 run next-step PRNG;
    //     prefetch next eval's P0F -> fB (all waves)
    load_frags<4, 8192>(fB, P + OFF_P0F, voff);
    __builtin_amdgcn_sched_barrier(0);
    if (wave < 8) {
      f32x4 acc = {0.f, 0.f, 0.f, 0.f};
#pragma unroll
      for (int kt = 0; kt < 8; ++kt) {
        bf16x8 a = *reinterpret_cast<const bf16x8*>(&sm.dpA[row16][kt * 32 + g * 8]);
        acc = __builtin_amdgcn_mfma_f32_16x16x32_bf16(a, fA[kt], acc, 0, 0, 0);
      }
      if (c < H_DIM) {
#pragma unroll
        for (int reg = 0; reg < 4; ++reg)
          sm.z_s[(g * 4 + reg) * H_DIM + c] = acc[reg];
      }
    } else if (next_s >= 0) {
      const uint32_t ka = sm.keyA[next_s], kb = sm.keyB[next_s];
#pragma unroll
      for (int rr = 0; rr < 2; ++rr) {
        const int r = (wave - 8) * 2 + rr;
#pragma unroll
        for (int it = 0; it < 2; ++it) {
          const int h = lane + it * 64;
          if (h < H_DIM) {
            const uint32_t f = (uint32_t)(blk * (ROWS * H_DIM) + r * H_DIM + h);
            uint32_t o0, o1;
            threefry2x32(ka, kb, 0u, f, o0, o1);
            const uint32_t bits = o0 ^ o1;
            const float fr = __uint_as_float((bits >> 9) | 0x3F800000u) - 1.0f;
            const float minv = -0.99999994f;  // nextafter(-1, 0)
            const float u = fmaxf(fr * 2.0f + minv, minv);
            const float n = 1.41421354f * erfinv_f32(u);
            sm.dw_s[r * H_DIM + h] = n * sqdt;
          }
        }
      }
    }
    __syncthreads();
  };

  // initial evaluation at t = 0 (also generates dW for step 0)
  mlp_eval(nullptr, 0);

  for (int s = 0; s < T_STEPS; ++s) {
    // ---- P8: y_tilde + x-update + next actI; wave w owns row w ----
    const float tv = t0v + (float)(s + 1) * dtv;
    {
      const int base = wave * H_DIM;
      const int h0 = lane;                 // < 100 always (lane<64)
      const int h1 = lane + 64;            // valid if < 100
      const float xv0 = sm.x_s[base + h0];
      const float zv0 = sm.z_s[base + h0];
      const float dw0 = sm.dw_s[base + h0];
      float s1 = xv0 * zv0;
      float s2 = zv0 * (0.4f * xv0) * dw0;
      float xv1 = 0.f, dw1 = 0.f;
      if (h1 < H_DIM) {
        xv1 = sm.x_s[base + h1];
        const float zv1 = sm.z_s[base + h1];
        dw1 = sm.dw_s[base + h1];
        s1 += xv1 * zv1;
        s2 += zv1 * (0.4f * xv1) * dw1;
      }
#pragma unroll
      for (int off = 32; off >= 1; off >>= 1) {
        s1 += __shfl_xor(s1, off, 64);
        s2 += __shfl_xor(s2, off, 64);
      }
      if (lane == 0) {
        const float yv = sm.y_s[wave];
        const float phi = 0.05f * (yv - s1);
        out_yt[(size_t)s * B_TRAJ + row0 + wave] = yv + phi * dtv + s2;
        sm.actI[wave][0] = f2bf(tv);
      }
      {
        const float x1 = xv0 + (0.4f * xv0) * dw0;
        sm.x_s[base + h0] = x1;
        sm.actI[wave][1 + h0] = f2bf(x1);
        out_xs[(size_t)s * (B_TRAJ * H_DIM) + (size_t)(row0 + wave) * H_DIM + h0] = x1;
        if (h1 < H_DIM) {
          const float x1b = xv1 + (0.4f * xv1) * dw1;
          sm.x_s[base + h1] = x1b;
          sm.actI[wave][1 + h1] = f2bf(x1b);
          out_xs[(size_t)s * (B_TRAJ * H_DIM) + (size_t)(row0 + wave) * H_DIM + h1] = x1b;
        }
      }
    }
    __syncthreads();

    mlp_eval(out_ys + (size_t)s * B_TRAJ, (s + 1 < T_STEPS) ? s + 1 : -1);
  }

  for (int e = tid; e < ROWS * H_DIM; e += THREADS) {
    out_xfin[(size_t)row0 * H_DIM + e] = sm.x_s[e];
    out_zfin[(size_t)row0 * H_DIM + e] = sm.z_s[e];
  }
  if (tid < ROWS) out_yfin[row0 + tid] = sm.y_s[tid];
}

extern "C" void kernel_launch(void* const* d_in, const int* in_sizes, int n_in,
                              void* d_out, int out_size, void* d_ws, size_t ws_size,
                              hipStream_t stream) {
  (void)in_sizes; (void)n_in; (void)ws_size; (void)out_size;
  const float* x0 = (const float*)d_in[0];
  const float* t0 = (const float*)d_in[1];
  const float* dt = (const float*)d_in[2];
  const float* W0 = (const float*)d_in[4];
  const float* b0 = (const float*)d_in[5];
  const float* W1 = (const float*)d_in[6];
  const float* b1 = (const float*)d_in[7];
  const float* W2 = (const float*)d_in[8];
  const float* b2 = (const float*)d_in[9];
  const float* W3 = (const float*)d_in[10];
  const float* b3 = (const float*)d_in[11];
  const float* W4 = (const float*)d_in[12];
  const float* b4 = (const float*)d_in[13];
  uint16_t* P = (uint16_t*)d_ws;
  float* out = (float*)d_out;

  hipLaunchKernelGGL(pack_kernel, dim3(PACK_GRID), dim3(256), 0, stream,
                     W0, W1, W2, W3, W4, P);
  hipLaunchKernelGGL(fbsde_kernel, dim3(NBLK), dim3(THREADS), 0, stream,
                     x0, t0, dt, b0, b1, b2, b3, W4, b4, P, out);
}

// Round 6
// 4749.898 us; speedup vs baseline: 1.0219x; 1.0219x over previous
//
#include <hip/hip_runtime.h>
#include <stdint.h>

#define B_TRAJ  4096
#define H_DIM   100
#define T_STEPS 100
#define ROWS    16
#define NBLK    256
#define THREADS 1024

typedef float    f32x4  __attribute__((ext_vector_type(4)));
typedef __bf16   bf16x8 __attribute__((ext_vector_type(8)));
typedef uint16_t u16x8  __attribute__((ext_vector_type(8)));

// ---- packed-weight layout in d_ws (u16/bf16 elements) ----
// within a pack: idx = (kt*N + n)*32 + kk ; kk = g*8 + e maps k = kt*32+kk
#define OFF_P0F  0        // [4][256][32]  W0[n][k]  (K pad 128)
#define OFF_P1F  32768    // [8][256][32]  W1[n][k]
#define OFF_P2F  98304
#define OFF_P3F  163840
#define OFF_P1B  229376   // [8][256][32]  W1[k][n]
#define OFF_P2B  294912
#define OFF_P3B  360448
#define OFF_P0B  425984   // [8][128][32]  W0[k][1+n] (N pad 128)
#define OFF_W4P  458752   // [256] bf16 W4 linear
#define OFF_KEYS 459008   // 200 x u32 (as 400 u16 slots)
#define PACK_TOTAL 459008
#define PACK_GRID ((PACK_TOTAL + 255) / 256)

__device__ __forceinline__ uint16_t f2bf(float f) {
  uint32_t u = __float_as_uint(f);
  uint32_t r = u + 0x7FFFu + ((u >> 16) & 1u);   // RNE
  return (uint16_t)(r >> 16);
}
__device__ __forceinline__ float bf2f(uint16_t u) {
  return __uint_as_float(((uint32_t)u) << 16);
}
__device__ __forceinline__ uint32_t rotl32(uint32_t v, int d) {
  return (v << d) | (v >> (32 - d));
}

// JAX Threefry-2x32, 20 rounds, exact key schedule.
__device__ __forceinline__ void threefry2x32(uint32_t k0, uint32_t k1,
                                             uint32_t x0, uint32_t x1,
                                             uint32_t& o0, uint32_t& o1) {
  const uint32_t k2 = k0 ^ k1 ^ 0x1BD11BDAu;
  x0 += k0; x1 += k1;
  x0 += x1; x1 = rotl32(x1, 13); x1 ^= x0;
  x0 += x1; x1 = rotl32(x1, 15); x1 ^= x0;
  x0 += x1; x1 = rotl32(x1, 26); x1 ^= x0;
  x0 += x1; x1 = rotl32(x1,  6); x1 ^= x0;
  x0 += k1; x1 += k2 + 1u;
  x0 += x1; x1 = rotl32(x1, 17); x1 ^= x0;
  x0 += x1; x1 = rotl32(x1, 29); x1 ^= x0;
  x0 += x1; x1 = rotl32(x1, 16); x1 ^= x0;
  x0 += x1; x1 = rotl32(x1, 24); x1 ^= x0;
  x0 += k2; x1 += k0 + 2u;
  x0 += x1; x1 = rotl32(x1, 13); x1 ^= x0;
  x0 += x1; x1 = rotl32(x1, 15); x1 ^= x0;
  x0 += x1; x1 = rotl32(x1, 26); x1 ^= x0;
  x0 += x1; x1 = rotl32(x1,  6); x1 ^= x0;
  x0 += k0; x1 += k1 + 3u;
  x0 += x1; x1 = rotl32(x1, 17); x1 ^= x0;
  x0 += x1; x1 = rotl32(x1, 29); x1 ^= x0;
  x0 += x1; x1 = rotl32(x1, 16); x1 ^= x0;
  x0 += x1; x1 = rotl32(x1, 24); x1 ^= x0;
  x0 += k1; x1 += k2 + 4u;
  x0 += x1; x1 = rotl32(x1, 13); x1 ^= x0;
  x0 += x1; x1 = rotl32(x1, 15); x1 ^= x0;
  x0 += x1; x1 = rotl32(x1, 26); x1 ^= x0;
  x0 += x1; x1 = rotl32(x1,  6); x1 ^= x0;
  x0 += k2; x1 += k0 + 5u;
  o0 = x0; o1 = x1;
}

// XLA ErfInv32 (Giles)
__device__ __forceinline__ float erfinv_f32(float x) {
  float w = -log1pf(-x * x);
  float p;
  if (w < 5.0f) {
    w = w - 2.5f;
    p = 2.81022636e-08f;
    p = fmaf(p, w, 3.43273939e-07f);
    p = fmaf(p, w, -3.5233877e-06f);
    p = fmaf(p, w, -4.39150654e-06f);
    p = fmaf(p, w, 0.00021858087f);
    p = fmaf(p, w, -0.00125372503f);
    p = fmaf(p, w, -0.00417768164f);
    p = fmaf(p, w, 0.246640727f);
    p = fmaf(p, w, 1.50140941f);
  } else {
    w = sqrtf(w) - 3.0f;
    p = -0.000200214257f;
    p = fmaf(p, w, 0.000100950558f);
    p = fmaf(p, w, 0.00134934322f);
    p = fmaf(p, w, -0.00367342844f);
    p = fmaf(p, w, 0.00573950773f);
    p = fmaf(p, w, -0.0076224613f);
    p = fmaf(p, w, 0.00943887047f);
    p = fmaf(p, w, 1.00167406f);
    p = fmaf(p, w, 2.83297682f);
  }
  return p * x;
}

// ---------------- weight packing + key chain (once per launch) ----------------
__global__ __launch_bounds__(256) void pack_kernel(
    const float* __restrict__ W0, const float* __restrict__ W1,
    const float* __restrict__ W2, const float* __restrict__ W3,
    const float* __restrict__ W4, uint16_t* __restrict__ P) {
  const int i = blockIdx.x * 256 + threadIdx.x;
  if (i == 0) {  // serial key chain: key(42), per step use child0, carry child1
    uint32_t* K = (uint32_t*)(P + OFF_KEYS);
    uint32_t c0 = 0u, c1 = 42u;
    for (int s = 0; s < T_STEPS; ++s) {
      uint32_t a0_, a1_, n0, n1;
      threefry2x32(c0, c1, 0u, 0u, a0_, a1_);
      threefry2x32(c0, c1, 0u, 1u, n0, n1);
      K[2 * s] = a0_; K[2 * s + 1] = a1_;
      c0 = n0; c1 = n1;
    }
  }
  if (i >= PACK_TOTAL) return;
  float v;
  if (i < OFF_P1F) {                 // P0F
    int e = i - OFF_P0F;
    int kk = e & 31, n = (e >> 5) & 255, kt = e >> 13;
    int k = kt * 32 + kk;
    v = (k < 101) ? W0[n * 101 + k] : 0.0f;
  } else if (i < OFF_P2F) {          // P1F
    int e = i - OFF_P1F;
    int kk = e & 31, n = (e >> 5) & 255, kt = e >> 13;
    v = W1[n * 256 + kt * 32 + kk];
  } else if (i < OFF_P3F) {          // P2F
    int e = i - OFF_P2F;
    int kk = e & 31, n = (e >> 5) & 255, kt = e >> 13;
    v = W2[n * 256 + kt * 32 + kk];
  } else if (i < OFF_P1B) {          // P3F
    int e = i - OFF_P3F;
    int kk = e & 31, n = (e >> 5) & 255, kt = e >> 13;
    v = W3[n * 256 + kt * 32 + kk];
  } else if (i < OFF_P2B) {          // P1B
    int e = i - OFF_P1B;
    int kk = e & 31, n = (e >> 5) & 255, kt = e >> 13;
    v = W1[(kt * 32 + kk) * 256 + n];
  } else if (i < OFF_P3B) {          // P2B
    int e = i - OFF_P2B;
    int kk = e & 31, n = (e >> 5) & 255, kt = e >> 13;
    v = W2[(kt * 32 + kk) * 256 + n];
  } else if (i < OFF_P0B) {          // P3B
    int e = i - OFF_P3B;
    int kk = e & 31, n = (e >> 5) & 255, kt = e >> 13;
    v = W3[(kt * 32 + kk) * 256 + n];
  } else if (i < OFF_W4P) {          // P0B
    int e = i - OFF_P0B;
    int kk = e & 31, n = (e >> 5) & 127, kt = e >> 12;
    int k = kt * 32 + kk;
    v = (n < 100) ? W0[k * 101 + 1 + n] : 0.0f;
  } else {                           // W4P
    v = W4[i - OFF_W4P];
  }
  P[i] = f2bf(v);
}

// ---------------- LDS ----------------
struct SmemT {
  uint16_t actI[ROWS][136];   // MLP input, K padded to 128
  uint16_t act1[ROWS][264];
  uint16_t act2[ROWS][264];
  uint16_t act3[ROWS][264];
  uint16_t act4[ROWS][264];
  uint16_t dpA[ROWS][264];
  uint16_t dpB[ROWS][264];
  float x_s[ROWS * H_DIM];
  float z_s[ROWS * H_DIM];
  float dw_s[ROWS * H_DIM];
  float y_s[ROWS];
  uint32_t keyA[T_STEPS], keyB[T_STEPS];
};

// ---------------- fragment load helpers ----------------
template<int KT, int STRIDE_EL>
__device__ __forceinline__ void load_frags(bf16x8 (&f)[8],
                                           const uint16_t* __restrict__ Pm,
                                           uint32_t voff) {
#pragma unroll
  for (int kt = 0; kt < KT; ++kt)
    f[kt] = *reinterpret_cast<const bf16x8*>(Pm + kt * STRIDE_EL + voff);
}

// ---------------- GEMM phase bodies (MFMA 16x16x32 bf16) ----------------
// D[r][c]: r=(lane>>4)*4+reg, c=lane&15 (m89).  A[r][kslot]: r=lane&15.
// kslot=(g,e) packing identical on A and B, so HW k-permutation cancels.

template<int INS>
__device__ __forceinline__ void fwd_do(const uint16_t (*in)[INS],
                                       const bf16x8 (&f)[8],
                                       const float* __restrict__ bias,
                                       uint16_t (*outb)[264],
                                       int row16, int g, int c) {
  const float bv = bias[c];
  f32x4 acc = {bv, bv, bv, bv};
#pragma unroll
  for (int kt = 0; kt < 8; ++kt) {
    bf16x8 a = *reinterpret_cast<const bf16x8*>(&in[row16][kt * 32 + g * 8]);
    acc = __builtin_amdgcn_mfma_f32_16x16x32_bf16(a, f[kt], acc, 0, 0, 0);
  }
#pragma unroll
  for (int reg = 0; reg < 4; ++reg)
    outb[g * 4 + reg][c] = f2bf(fmaxf(acc[reg], 0.0f));
}

__device__ __forceinline__ void bwd_do(const uint16_t (*in)[264],
                                       const bf16x8 (&f)[8],
                                       const uint16_t (*mact)[264],
                                       uint16_t (*outb)[264],
                                       int row16, int g, int c) {
  f32x4 acc = {0.f, 0.f, 0.f, 0.f};
#pragma unroll
  for (int kt = 0; kt < 8; ++kt) {
    bf16x8 a = *reinterpret_cast<const bf16x8*>(&in[row16][kt * 32 + g * 8]);
    acc = __builtin_amdgcn_mfma_f32_16x16x32_bf16(a, f[kt], acc, 0, 0, 0);
  }
#pragma unroll
  for (int reg = 0; reg < 4; ++reg) {
    const int r = g * 4 + reg;
    outb[r][c] = mact[r][c] ? f2bf(acc[reg]) : (uint16_t)0;
  }
}

// ---------------- main kernel ----------------
// __launch_bounds__(1024, 1): one 1024-thread block per CU -> VGPR cap 128.
// (1024,4) produced a 64-VGPR cap and catastrophic scratch spill (R4/R5:
// FETCH_SIZE 11 GB). The ping-pong needs 64 VGPR of fragments + ~40 working.
__global__ __launch_bounds__(THREADS, 1) void fbsde_kernel(
    const float* __restrict__ x0, const float* __restrict__ t0p,
    const float* __restrict__ dtp,
    const float* __restrict__ b0, const float* __restrict__ b1,
    const float* __restrict__ b2, const float* __restrict__ b3,
    const float* __restrict__ W4, const float* __restrict__ b4,
    const uint16_t* __restrict__ P, float* __restrict__ out) {
  __shared__ __align__(16) SmemT sm;

  const int tid = threadIdx.x;
  const int wave = tid >> 6, lane = tid & 63;
  const int row16 = lane & 15, g = lane >> 4;
  const int c = row16 + 16 * wave;
  const uint32_t voff = (uint32_t)(c * 32 + g * 8);   // fragment element offset
  const int blk = blockIdx.x;
  const int row0 = blk * ROWS;

  // strict ping-pong fragment buffers (the ONLY long-lived VGPR arrays)
  bf16x8 fA[8], fB[8];

  // ---- init ----
  if (tid < T_STEPS) {
    const uint32_t* K = (const uint32_t*)(P + OFF_KEYS);
    sm.keyA[tid] = K[2 * tid];
    sm.keyB[tid] = K[2 * tid + 1];
  }
  for (int e = tid; e < ROWS * H_DIM; e += THREADS)
    sm.x_s[e] = x0[row0 * H_DIM + e];
  for (int e = tid; e < ROWS * 136; e += THREADS) {
    const int r = e / 136, cc = e - r * 136;
    uint16_t v = 0;
    if (cc >= 1 && cc <= H_DIM) v = f2bf(x0[(row0 + r) * H_DIM + cc - 1]);
    sm.actI[r][cc] = v;   // cc==0 -> t=0.0 -> bf16 0
  }
  load_frags<4, 8192>(fB, P + OFF_P0F, voff);   // first eval's P0F
  const float t0v = t0p[0];
  const float dtv = dtp[0];
  const float sqdt = sqrtf(dtv);
  __syncthreads();

  float* const out_xfin = out;                                  // (B,H)
  float* const out_yfin = out + 409600;                         // (B,1)
  float* const out_zfin = out + 413696;                         // (B,H)
  float* const out_xs   = out + 823296;                         // (T,B,H)
  float* const out_yt   = out + 823296 + 40960000;              // (T,B,1)
  float* const out_ys   = out + 823296 + 40960000 + 409600;     // (T,B,1)

  // ---- one MLP fwd+VJP eval, ping-pong prefetch across all 8 phases ----
  // entry: fB = this eval's P0F. exit: fB = next eval's P0F.
  auto mlp_eval = [&](float* ys_out, int next_s) {
    // P0: use fB (P0F), prefetch P1F -> fA
    load_frags<8, 8192>(fA, P + OFF_P1F, voff);
    __builtin_amdgcn_sched_barrier(0);
    {
      const float bv = b0[c];
      f32x4 acc = {bv, bv, bv, bv};
#pragma unroll
      for (int kt = 0; kt < 4; ++kt) {
        bf16x8 a = *reinterpret_cast<const bf16x8*>(&sm.actI[row16][kt * 32 + g * 8]);
        acc = __builtin_amdgcn_mfma_f32_16x16x32_bf16(a, fB[kt], acc, 0, 0, 0);
      }
#pragma unroll
      for (int reg = 0; reg < 4; ++reg)
        sm.act1[g * 4 + reg][c] = f2bf(fmaxf(acc[reg], 0.0f));
    }
    __syncthreads();

    // P1: use fA (P1F), prefetch P2F -> fB
    load_frags<8, 8192>(fB, P + OFF_P2F, voff);
    __builtin_amdgcn_sched_barrier(0);
    fwd_do<264>(sm.act1, fA, b1, sm.act2, row16, g, c);
    __syncthreads();

    // P2: use fB (P2F), prefetch P3F -> fA
    load_frags<8, 8192>(fA, P + OFF_P3F, voff);
    __builtin_amdgcn_sched_barrier(0);
    fwd_do<264>(sm.act2, fB, b2, sm.act3, row16, g, c);
    __syncthreads();

    // P3: use fA (P3F), prefetch P3B -> fB
    load_frags<8, 8192>(fB, P + OFF_P3B, voff);
    __builtin_amdgcn_sched_barrier(0);
    fwd_do<264>(sm.act3, fA, b3, sm.act4, row16, g, c);
    __syncthreads();

    // P4: use fB (P3B): y-reduce + bwd3 (dp4 built on the fly);
    //     prefetch P2B -> fA
    load_frags<8, 8192>(fA, P + OFF_P2B, voff);
    __builtin_amdgcn_sched_barrier(0);
    {
      float s = 0.0f;
#pragma unroll
      for (int m = 0; m < 4; ++m) {
        const int j = lane + (m << 6);
        s += bf2f(sm.act4[wave][j]) * W4[j];
      }
#pragma unroll
      for (int off = 32; off >= 1; off >>= 1) s += __shfl_xor(s, off, 64);
      if (lane == 0) {
        const float yv = s + b4[0];
        sm.y_s[wave] = yv;
        if (ys_out) ys_out[row0 + wave] = yv;
      }
      const uint16_t* W4P = P + OFF_W4P;
      f32x4 acc = {0.f, 0.f, 0.f, 0.f};
#pragma unroll
      for (int kt = 0; kt < 8; ++kt) {
        u16x8 au = *reinterpret_cast<const u16x8*>(&sm.act4[row16][kt * 32 + g * 8]);
        u16x8 wu = *reinterpret_cast<const u16x8*>(&W4P[kt * 32 + g * 8]);
        u16x8 sel;
#pragma unroll
        for (int e = 0; e < 8; ++e) sel[e] = au[e] ? wu[e] : (uint16_t)0;
        acc = __builtin_amdgcn_mfma_f32_16x16x32_bf16(
            __builtin_bit_cast(bf16x8, sel), fB[kt], acc, 0, 0, 0);
      }
#pragma unroll
      for (int reg = 0; reg < 4; ++reg) {
        const int r = g * 4 + reg;
        sm.dpA[r][c] = sm.act3[r][c] ? f2bf(acc[reg]) : (uint16_t)0;
      }
    }
    __syncthreads();

    // P5: use fA (P2B), prefetch P1B -> fB
    load_frags<8, 8192>(fB, P + OFF_P1B, voff);
    __builtin_amdgcn_sched_barrier(0);
    bwd_do(sm.dpA, fA, sm.act2, sm.dpB, row16, g, c);
    __syncthreads();

    // P6: use fB (P1B), prefetch P0B -> fA (waves 0-7 only; c<128 valid)
    if (wave < 8) load_frags<8, 4096>(fA, P + OFF_P0B, voff);
    __builtin_amdgcn_sched_barrier(0);
    bwd_do(sm.dpB, fB, sm.act1, sm.dpA, row16, g, c);
    __syncthreads();

    // P7: use fA (P0B) for bwd0 on waves 0-7; waves 8-15 run next-step PRNG;
    //     prefetch next eval's P0F -> fB (all waves)
    load_frags<4, 8192>(fB, P + OFF_P0F, voff);
    __builtin_amdgcn_sched_barrier(0);
    if (wave < 8) {
      f32x4 acc = {0.f, 0.f, 0.f, 0.f};
#pragma unroll
      for (int kt = 0; kt < 8; ++kt) {
        bf16x8 a = *reinterpret_cast<const bf16x8*>(&sm.dpA[row16][kt * 32 + g * 8]);
        acc = __builtin_amdgcn_mfma_f32_16x16x32_bf16(a, fA[kt], acc, 0, 0, 0);
      }
      if (c < H_DIM) {
#pragma unroll
        for (int reg = 0; reg < 4; ++reg)
          sm.z_s[(g * 4 + reg) * H_DIM + c] = acc[reg];
      }
    } else if (next_s >= 0) {
      const uint32_t ka = sm.keyA[next_s], kb = sm.keyB[next_s];
#pragma unroll
      for (int rr = 0; rr < 2; ++rr) {
        const int r = (wave - 8) * 2 + rr;
#pragma unroll
        for (int it = 0; it < 2; ++it) {
          const int h = lane + it * 64;
          if (h < H_DIM) {
            const uint32_t f = (uint32_t)(blk * (ROWS * H_DIM) + r * H_DIM + h);
            uint32_t o0, o1;
            threefry2x32(ka, kb, 0u, f, o0, o1);
            const uint32_t bits = o0 ^ o1;
            const float fr = __uint_as_float((bits >> 9) | 0x3F800000u) - 1.0f;
            const float minv = -0.99999994f;  // nextafter(-1, 0)
            const float u = fmaxf(fr * 2.0f + minv, minv);
            const float n = 1.41421354f * erfinv_f32(u);
            sm.dw_s[r * H_DIM + h] = n * sqdt;
          }
        }
      }
    }
    __syncthreads();
  };

  // initial evaluation at t = 0 (also generates dW for step 0)
  mlp_eval(nullptr, 0);

  for (int s = 0; s < T_STEPS; ++s) {
    // ---- P8: y_tilde + x-update + next actI; wave w owns row w ----
    const float tv = t0v + (float)(s + 1) * dtv;
    {
      const int base = wave * H_DIM;
      const int h0 = lane;                 // < 100 always (lane<64)
      const int h1 = lane + 64;            // valid if < 100
      const float xv0 = sm.x_s[base + h0];
      const float zv0 = sm.z_s[base + h0];
      const float dw0 = sm.dw_s[base + h0];
      float s1 = xv0 * zv0;
      float s2 = zv0 * (0.4f * xv0) * dw0;
      float xv1 = 0.f, dw1 = 0.f;
      if (h1 < H_DIM) {
        xv1 = sm.x_s[base + h1];
        const float zv1 = sm.z_s[base + h1];
        dw1 = sm.dw_s[base + h1];
        s1 += xv1 * zv1;
        s2 += zv1 * (0.4f * xv1) * dw1;
      }
#pragma unroll
      for (int off = 32; off >= 1; off >>= 1) {
        s1 += __shfl_xor(s1, off, 64);
        s2 += __shfl_xor(s2, off, 64);
      }
      if (lane == 0) {
        const float yv = sm.y_s[wave];
        const float phi = 0.05f * (yv - s1);
        out_yt[(size_t)s * B_TRAJ + row0 + wave] = yv + phi * dtv + s2;
        sm.actI[wave][0] = f2bf(tv);
      }
      {
        const float x1 = xv0 + (0.4f * xv0) * dw0;
        sm.x_s[base + h0] = x1;
        sm.actI[wave][1 + h0] = f2bf(x1);
        out_xs[(size_t)s * (B_TRAJ * H_DIM) + (size_t)(row0 + wave) * H_DIM + h0] = x1;
        if (h1 < H_DIM) {
          const float x1b = xv1 + (0.4f * xv1) * dw1;
          sm.x_s[base + h1] = x1b;
          sm.actI[wave][1 + h1] = f2bf(x1b);
          out_xs[(size_t)s * (B_TRAJ * H_DIM) + (size_t)(row0 + wave) * H_DIM + h1] = x1b;
        }
      }
    }
    __syncthreads();

    mlp_eval(out_ys + (size_t)s * B_TRAJ, (s + 1 < T_STEPS) ? s + 1 : -1);
  }

  for (int e = tid; e < ROWS * H_DIM; e += THREADS) {
    out_xfin[(size_t)row0 * H_DIM + e] = sm.x_s[e];
    out_zfin[(size_t)row0 * H_DIM + e] = sm.z_s[e];
  }
  if (tid < ROWS) out_yfin[row0 + tid] = sm.y_s[tid];
}

extern "C" void kernel_launch(void* const* d_in, const int* in_sizes, int n_in,
                              void* d_out, int out_size, void* d_ws, size_t ws_size,
                              hipStream_t stream) {
  (void)in_sizes; (void)n_in; (void)ws_size; (void)out_size;
  const float* x0 = (const float*)d_in[0];
  const float* t0 = (const float*)d_in[1];
  const float* dt = (const float*)d_in[2];
  const float* W0 = (const float*)d_in[4];
  const float* b0 = (const float*)d_in[5];
  const float* W1 = (const float*)d_in[6];
  const float* b1 = (const float*)d_in[7];
  const float* W2 = (const float*)d_in[8];
  const float* b2 = (const float*)d_in[9];
  const float* W3 = (const float*)d_in[10];
  const float* b3 = (const float*)d_in[11];
  const float* W4 = (const float*)d_in[12];
  const float* b4 = (const float*)d_in[13];
  uint16_t* P = (uint16_t*)d_ws;
  float* out = (float*)d_out;

  hipLaunchKernelGGL(pack_kernel, dim3(PACK_GRID), dim3(256), 0, stream,
                     W0, W1, W2, W3, W4, P);
  hipLaunchKernelGGL(fbsde_kernel, dim3(NBLK), dim3(THREADS), 0, stream,
                     x0, t0, dt, b0, b1, b2, b3, W4, b4, P, out);
}

// Round 7
// 4583.084 us; speedup vs baseline: 1.0591x; 1.0364x over previous
//
#include <hip/hip_runtime.h>
#include <stdint.h>

#define B_TRAJ  4096
#define H_DIM   100
#define T_STEPS 100
#define ROWS    16
#define NBLK    256
#define THREADS 1024

typedef float    f32x4  __attribute__((ext_vector_type(4)));
typedef __bf16   bf16x8 __attribute__((ext_vector_type(8)));
typedef uint16_t u16x8  __attribute__((ext_vector_type(8)));

// ---- packed-weight layout in d_ws (u16/bf16 elements) ----
// within a pack: idx = (kt*N + n)*32 + kk ; kk = g*8 + e maps k = kt*32+kk
#define OFF_P0F  0        // [4][256][32]  W0[n][k]  (K pad 128)
#define OFF_P1F  32768    // [8][256][32]  W1[n][k]
#define OFF_P2F  98304
#define OFF_P3F  163840
#define OFF_P1B  229376   // [8][256][32]  W1[k][n]
#define OFF_P2B  294912
#define OFF_P3B  360448
#define OFF_P0B  425984   // [8][128][32]  W0[k][1+n] (N pad 128)
#define OFF_W4P  458752   // [256] bf16 W4 linear
#define OFF_KEYS 459008   // 200 x u32 (as 400 u16 slots)
#define PACK_TOTAL 459008
#define PACK_GRID ((PACK_TOTAL + 255) / 256)

__device__ __forceinline__ uint16_t f2bf(float f) {
  uint32_t u = __float_as_uint(f);
  uint32_t r = u + 0x7FFFu + ((u >> 16) & 1u);   // RNE
  return (uint16_t)(r >> 16);
}
__device__ __forceinline__ float bf2f(uint16_t u) {
  return __uint_as_float(((uint32_t)u) << 16);
}
__device__ __forceinline__ uint32_t rotl32(uint32_t v, int d) {
  return (v << d) | (v >> (32 - d));
}

// JAX Threefry-2x32, 20 rounds, exact key schedule.
__device__ __forceinline__ void threefry2x32(uint32_t k0, uint32_t k1,
                                             uint32_t x0, uint32_t x1,
                                             uint32_t& o0, uint32_t& o1) {
  const uint32_t k2 = k0 ^ k1 ^ 0x1BD11BDAu;
  x0 += k0; x1 += k1;
  x0 += x1; x1 = rotl32(x1, 13); x1 ^= x0;
  x0 += x1; x1 = rotl32(x1, 15); x1 ^= x0;
  x0 += x1; x1 = rotl32(x1, 26); x1 ^= x0;
  x0 += x1; x1 = rotl32(x1,  6); x1 ^= x0;
  x0 += k1; x1 += k2 + 1u;
  x0 += x1; x1 = rotl32(x1, 17); x1 ^= x0;
  x0 += x1; x1 = rotl32(x1, 29); x1 ^= x0;
  x0 += x1; x1 = rotl32(x1, 16); x1 ^= x0;
  x0 += x1; x1 = rotl32(x1, 24); x1 ^= x0;
  x0 += k2; x1 += k0 + 2u;
  x0 += x1; x1 = rotl32(x1, 13); x1 ^= x0;
  x0 += x1; x1 = rotl32(x1, 15); x1 ^= x0;
  x0 += x1; x1 = rotl32(x1, 26); x1 ^= x0;
  x0 += x1; x1 = rotl32(x1,  6); x1 ^= x0;
  x0 += k0; x1 += k1 + 3u;
  x0 += x1; x1 = rotl32(x1, 17); x1 ^= x0;
  x0 += x1; x1 = rotl32(x1, 29); x1 ^= x0;
  x0 += x1; x1 = rotl32(x1, 16); x1 ^= x0;
  x0 += x1; x1 = rotl32(x1, 24); x1 ^= x0;
  x0 += k1; x1 += k2 + 4u;
  x0 += x1; x1 = rotl32(x1, 13); x1 ^= x0;
  x0 += x1; x1 = rotl32(x1, 15); x1 ^= x0;
  x0 += x1; x1 = rotl32(x1, 26); x1 ^= x0;
  x0 += x1; x1 = rotl32(x1,  6); x1 ^= x0;
  x0 += k2; x1 += k0 + 5u;
  o0 = x0; o1 = x1;
}

// XLA ErfInv32 (Giles)
__device__ __forceinline__ float erfinv_f32(float x) {
  float w = -log1pf(-x * x);
  float p;
  if (w < 5.0f) {
    w = w - 2.5f;
    p = 2.81022636e-08f;
    p = fmaf(p, w, 3.43273939e-07f);
    p = fmaf(p, w, -3.5233877e-06f);
    p = fmaf(p, w, -4.39150654e-06f);
    p = fmaf(p, w, 0.00021858087f);
    p = fmaf(p, w, -0.00125372503f);
    p = fmaf(p, w, -0.00417768164f);
    p = fmaf(p, w, 0.246640727f);
    p = fmaf(p, w, 1.50140941f);
  } else {
    w = sqrtf(w) - 3.0f;
    p = -0.000200214257f;
    p = fmaf(p, w, 0.000100950558f);
    p = fmaf(p, w, 0.00134934322f);
    p = fmaf(p, w, -0.00367342844f);
    p = fmaf(p, w, 0.00573950773f);
    p = fmaf(p, w, -0.0076224613f);
    p = fmaf(p, w, 0.00943887047f);
    p = fmaf(p, w, 1.00167406f);
    p = fmaf(p, w, 2.83297682f);
  }
  return p * x;
}

// ---------------- weight packing + key chain (once per launch) ----------------
__global__ __launch_bounds__(256) void pack_kernel(
    const float* __restrict__ W0, const float* __restrict__ W1,
    const float* __restrict__ W2, const float* __restrict__ W3,
    const float* __restrict__ W4, uint16_t* __restrict__ P) {
  const int i = blockIdx.x * 256 + threadIdx.x;
  if (i == 0) {  // serial key chain: key(42), per step use child0, carry child1
    uint32_t* K = (uint32_t*)(P + OFF_KEYS);
    uint32_t c0 = 0u, c1 = 42u;
    for (int s = 0; s < T_STEPS; ++s) {
      uint32_t a0_, a1_, n0, n1;
      threefry2x32(c0, c1, 0u, 0u, a0_, a1_);
      threefry2x32(c0, c1, 0u, 1u, n0, n1);
      K[2 * s] = a0_; K[2 * s + 1] = a1_;
      c0 = n0; c1 = n1;
    }
  }
  if (i >= PACK_TOTAL) return;
  float v;
  if (i < OFF_P1F) {                 // P0F
    int e = i - OFF_P0F;
    int kk = e & 31, n = (e >> 5) & 255, kt = e >> 13;
    int k = kt * 32 + kk;
    v = (k < 101) ? W0[n * 101 + k] : 0.0f;
  } else if (i < OFF_P2F) {          // P1F
    int e = i - OFF_P1F;
    int kk = e & 31, n = (e >> 5) & 255, kt = e >> 13;
    v = W1[n * 256 + kt * 32 + kk];
  } else if (i < OFF_P3F) {          // P2F
    int e = i - OFF_P2F;
    int kk = e & 31, n = (e >> 5) & 255, kt = e >> 13;
    v = W2[n * 256 + kt * 32 + kk];
  } else if (i < OFF_P1B) {          // P3F
    int e = i - OFF_P3F;
    int kk = e & 31, n = (e >> 5) & 255, kt = e >> 13;
    v = W3[n * 256 + kt * 32 + kk];
  } else if (i < OFF_P2B) {          // P1B
    int e = i - OFF_P1B;
    int kk = e & 31, n = (e >> 5) & 255, kt = e >> 13;
    v = W1[(kt * 32 + kk) * 256 + n];
  } else if (i < OFF_P3B) {          // P2B
    int e = i - OFF_P2B;
    int kk = e & 31, n = (e >> 5) & 255, kt = e >> 13;
    v = W2[(kt * 32 + kk) * 256 + n];
  } else if (i < OFF_P0B) {          // P3B
    int e = i - OFF_P3B;
    int kk = e & 31, n = (e >> 5) & 255, kt = e >> 13;
    v = W3[(kt * 32 + kk) * 256 + n];
  } else if (i < OFF_W4P) {          // P0B
    int e = i - OFF_P0B;
    int kk = e & 31, n = (e >> 5) & 127, kt = e >> 12;
    int k = kt * 32 + kk;
    v = (n < 100) ? W0[k * 101 + 1 + n] : 0.0f;
  } else {                           // W4P
    v = W4[i - OFF_W4P];
  }
  P[i] = f2bf(v);
}

// ---------------- LDS ----------------
struct SmemT {
  uint16_t actI[ROWS][136];   // MLP input, K padded to 128
  uint16_t act1[ROWS][264];
  uint16_t act2[ROWS][264];
  uint16_t act3[ROWS][264];
  uint16_t act4[ROWS][264];
  uint16_t dpA[ROWS][264];
  uint16_t dpB[ROWS][264];
  float x_s[ROWS * H_DIM];
  float z_s[ROWS * H_DIM];
  float dw_s[ROWS * H_DIM];
  float y_s[ROWS];
  uint32_t keyA[T_STEPS], keyB[T_STEPS];
};

// ---------------- fragment load helper ----------------
template<int KT, int STRIDE_EL>
__device__ __forceinline__ void load_frags(bf16x8 (&f)[8],
                                           const uint16_t* __restrict__ Pm,
                                           uint32_t voff) {
#pragma unroll
  for (int kt = 0; kt < KT; ++kt)
    f[kt] = *reinterpret_cast<const bf16x8*>(Pm + kt * STRIDE_EL + voff);
}

// ---------------- GEMM phase bodies (MFMA 16x16x32 bf16) ----------------
// D[r][c]: r=(lane>>4)*4+reg, c=lane&15 (m89).  A[r][kslot]: r=lane&15.
// kslot=(g,e) packing identical on A and B, so HW k-permutation cancels.

template<int INS>
__device__ __forceinline__ void fwd_do(const uint16_t (*in)[INS],
                                       const bf16x8 (&f)[8],
                                       const float* __restrict__ bias,
                                       uint16_t (*outb)[264],
                                       int row16, int g, int c) {
  const float bv = bias[c];
  f32x4 acc = {bv, bv, bv, bv};
#pragma unroll
  for (int kt = 0; kt < 8; ++kt) {
    bf16x8 a = *reinterpret_cast<const bf16x8*>(&in[row16][kt * 32 + g * 8]);
    acc = __builtin_amdgcn_mfma_f32_16x16x32_bf16(a, f[kt], acc, 0, 0, 0);
  }
#pragma unroll
  for (int reg = 0; reg < 4; ++reg)
    outb[g * 4 + reg][c] = f2bf(fmaxf(acc[reg], 0.0f));
}

__device__ __forceinline__ void bwd_do(const uint16_t (*in)[264],
                                       const bf16x8 (&f)[8],
                                       const uint16_t (*mact)[264],
                                       uint16_t (*outb)[264],
                                       int row16, int g, int c) {
  f32x4 acc = {0.f, 0.f, 0.f, 0.f};
#pragma unroll
  for (int kt = 0; kt < 8; ++kt) {
    bf16x8 a = *reinterpret_cast<const bf16x8*>(&in[row16][kt * 32 + g * 8]);
    acc = __builtin_amdgcn_mfma_f32_16x16x32_bf16(a, f[kt], acc, 0, 0, 0);
  }
#pragma unroll
  for (int reg = 0; reg < 4; ++reg) {
    const int r = g * 4 + reg;
    outb[r][c] = mact[r][c] ? f2bf(acc[reg]) : (uint16_t)0;
  }
}

// ---------------- main kernel ----------------
// NOTE: the MLP eval body appears EXACTLY ONCE, inline in the kernel body.
// R4-R6 wrapped it in a [&]-capturing lambda called from 2 sites; the
// compiler outlined it, which forced the fragment arrays to scratch
// (VGPR_Count 64, FETCH_SIZE 11 GB of spill traffic).
__global__ __launch_bounds__(THREADS) void fbsde_kernel(
    const float* __restrict__ x0, const float* __restrict__ t0p,
    const float* __restrict__ dtp,
    const float* __restrict__ b0, const float* __restrict__ b1,
    const float* __restrict__ b2, const float* __restrict__ b3,
    const float* __restrict__ W4, const float* __restrict__ b4,
    const uint16_t* __restrict__ P, float* __restrict__ out) {
  __shared__ __align__(16) SmemT sm;

  const int tid = threadIdx.x;
  const int wave = tid >> 6, lane = tid & 63;
  const int row16 = lane & 15, g = lane >> 4;
  const int c = row16 + 16 * wave;
  const uint32_t voff = (uint32_t)(c * 32 + g * 8);   // fragment element offset
  const int blk = blockIdx.x;
  const int row0 = blk * ROWS;

  // strict ping-pong fragment buffers (compile-time indexed only)
  bf16x8 fA[8], fB[8];

  // ---- init ----
  if (tid < T_STEPS) {
    const uint32_t* K = (const uint32_t*)(P + OFF_KEYS);
    sm.keyA[tid] = K[2 * tid];
    sm.keyB[tid] = K[2 * tid + 1];
  }
  for (int e = tid; e < ROWS * H_DIM; e += THREADS)
    sm.x_s[e] = x0[row0 * H_DIM + e];
  for (int e = tid; e < ROWS * 136; e += THREADS) {
    const int r = e / 136, cc = e - r * 136;
    uint16_t v = 0;
    if (cc >= 1 && cc <= H_DIM) v = f2bf(x0[(row0 + r) * H_DIM + cc - 1]);
    sm.actI[r][cc] = v;   // cc==0 -> t=0.0 -> bf16 0
  }
  load_frags<4, 8192>(fB, P + OFF_P0F, voff);   // first eval's P0F
  const float t0v = t0p[0];
  const float dtv = dtp[0];
  const float sqdt = sqrtf(dtv);
  __syncthreads();

  float* const out_xfin = out;                                  // (B,H)
  float* const out_yfin = out + 409600;                         // (B,1)
  float* const out_zfin = out + 413696;                         // (B,H)
  float* const out_xs   = out + 823296;                         // (T,B,H)
  float* const out_yt   = out + 823296 + 40960000;              // (T,B,1)
  float* const out_ys   = out + 823296 + 40960000 + 409600;     // (T,B,1)

  // it = 0: initial eval at t=0 (no SDE phase, no ys write, gen dW for step 0)
  // it>=1:  SDE phase for s=it-1, then eval (writes ys[s], gen dW for step it)
  for (int it = 0; it <= T_STEPS; ++it) {
    const int s = it - 1;

    if (it > 0) {
      // ---- SDE phase: y_tilde + x-update + next actI; wave w owns row w ----
      const float tv = t0v + (float)it * dtv;
      const int base = wave * H_DIM;
      const int h0 = lane;                 // < 100 always (lane<64)
      const int h1 = lane + 64;            // valid if < 100
      const float xv0 = sm.x_s[base + h0];
      const float zv0 = sm.z_s[base + h0];
      const float dw0 = sm.dw_s[base + h0];
      float s1 = xv0 * zv0;
      float s2 = zv0 * (0.4f * xv0) * dw0;
      float xv1 = 0.f, dw1 = 0.f;
      if (h1 < H_DIM) {
        xv1 = sm.x_s[base + h1];
        const float zv1 = sm.z_s[base + h1];
        dw1 = sm.dw_s[base + h1];
        s1 += xv1 * zv1;
        s2 += zv1 * (0.4f * xv1) * dw1;
      }
#pragma unroll
      for (int off = 32; off >= 1; off >>= 1) {
        s1 += __shfl_xor(s1, off, 64);
        s2 += __shfl_xor(s2, off, 64);
      }
      if (lane == 0) {
        const float yv = sm.y_s[wave];
        const float phi = 0.05f * (yv - s1);
        out_yt[(size_t)s * B_TRAJ + row0 + wave] = yv + phi * dtv + s2;
        sm.actI[wave][0] = f2bf(tv);
      }
      {
        const float x1 = xv0 + (0.4f * xv0) * dw0;
        sm.x_s[base + h0] = x1;
        sm.actI[wave][1 + h0] = f2bf(x1);
        out_xs[(size_t)s * (B_TRAJ * H_DIM) + (size_t)(row0 + wave) * H_DIM + h0] = x1;
        if (h1 < H_DIM) {
          const float x1b = xv1 + (0.4f * xv1) * dw1;
          sm.x_s[base + h1] = x1b;
          sm.actI[wave][1 + h1] = f2bf(x1b);
          out_xs[(size_t)s * (B_TRAJ * H_DIM) + (size_t)(row0 + wave) * H_DIM + h1] = x1b;
        }
      }
      __syncthreads();
    }

    // ======== MLP fwd + VJP eval (entry: fB = this eval's P0F) ========
    float* const ys_out = (it > 0) ? (out_ys + (size_t)s * B_TRAJ) : nullptr;
    const int next_s = (it < T_STEPS) ? it : -1;

    // P0: use fB (P0F), prefetch P1F -> fA
    load_frags<8, 8192>(fA, P + OFF_P1F, voff);
    __builtin_amdgcn_sched_barrier(0);
    {
      const float bv = b0[c];
      f32x4 acc = {bv, bv, bv, bv};
#pragma unroll
      for (int kt = 0; kt < 4; ++kt) {
        bf16x8 a = *reinterpret_cast<const bf16x8*>(&sm.actI[row16][kt * 32 + g * 8]);
        acc = __builtin_amdgcn_mfma_f32_16x16x32_bf16(a, fB[kt], acc, 0, 0, 0);
      }
#pragma unroll
      for (int reg = 0; reg < 4; ++reg)
        sm.act1[g * 4 + reg][c] = f2bf(fmaxf(acc[reg], 0.0f));
    }
    __syncthreads();

    // P1: use fA (P1F), prefetch P2F -> fB
    load_frags<8, 8192>(fB, P + OFF_P2F, voff);
    __builtin_amdgcn_sched_barrier(0);
    fwd_do<264>(sm.act1, fA, b1, sm.act2, row16, g, c);
    __syncthreads();

    // P2: use fB (P2F), prefetch P3F -> fA
    load_frags<8, 8192>(fA, P + OFF_P3F, voff);
    __builtin_amdgcn_sched_barrier(0);
    fwd_do<264>(sm.act2, fB, b2, sm.act3, row16, g, c);
    __syncthreads();

    // P3: use fA (P3F), prefetch P3B -> fB
    load_frags<8, 8192>(fB, P + OFF_P3B, voff);
    __builtin_amdgcn_sched_barrier(0);
    fwd_do<264>(sm.act3, fA, b3, sm.act4, row16, g, c);
    __syncthreads();

    // P4: use fB (P3B): y-reduce + bwd3 (dp4 on the fly); prefetch P2B -> fA
    load_frags<8, 8192>(fA, P + OFF_P2B, voff);
    __builtin_amdgcn_sched_barrier(0);
    {
      float sy = 0.0f;
#pragma unroll
      for (int m = 0; m < 4; ++m) {
        const int j = lane + (m << 6);
        sy += bf2f(sm.act4[wave][j]) * W4[j];
      }
#pragma unroll
      for (int off = 32; off >= 1; off >>= 1) sy += __shfl_xor(sy, off, 64);
      if (lane == 0) {
        const float yv = sy + b4[0];
        sm.y_s[wave] = yv;
        if (ys_out) ys_out[row0 + wave] = yv;
      }
      const uint16_t* W4P = P + OFF_W4P;
      f32x4 acc = {0.f, 0.f, 0.f, 0.f};
#pragma unroll
      for (int kt = 0; kt < 8; ++kt) {
        u16x8 au = *reinterpret_cast<const u16x8*>(&sm.act4[row16][kt * 32 + g * 8]);
        u16x8 wu = *reinterpret_cast<const u16x8*>(&W4P[kt * 32 + g * 8]);
        u16x8 sel;
#pragma unroll
        for (int e = 0; e < 8; ++e) sel[e] = au[e] ? wu[e] : (uint16_t)0;
        acc = __builtin_amdgcn_mfma_f32_16x16x32_bf16(
            __builtin_bit_cast(bf16x8, sel), fB[kt], acc, 0, 0, 0);
      }
#pragma unroll
      for (int reg = 0; reg < 4; ++reg) {
        const int r = g * 4 + reg;
        sm.dpA[r][c] = sm.act3[r][c] ? f2bf(acc[reg]) : (uint16_t)0;
      }
    }
    __syncthreads();

    // P5: use fA (P2B), prefetch P1B -> fB
    load_frags<8, 8192>(fB, P + OFF_P1B, voff);
    __builtin_amdgcn_sched_barrier(0);
    bwd_do(sm.dpA, fA, sm.act2, sm.dpB, row16, g, c);
    __syncthreads();

    // P6: use fB (P1B), prefetch P0B -> fA (waves 0-7 only; c<128 valid)
    if (wave < 8) load_frags<8, 4096>(fA, P + OFF_P0B, voff);
    __builtin_amdgcn_sched_barrier(0);
    bwd_do(sm.dpB, fB, sm.act1, sm.dpA, row16, g, c);
    __syncthreads();

    // P7: bwd0 on waves 0-7 (z out); waves 8-15 run next-step PRNG;
    //     prefetch next eval's P0F -> fB (all waves)
    load_frags<4, 8192>(fB, P + OFF_P0F, voff);
    __builtin_amdgcn_sched_barrier(0);
    if (wave < 8) {
      f32x4 acc = {0.f, 0.f, 0.f, 0.f};
#pragma unroll
      for (int kt = 0; kt < 8; ++kt) {
        bf16x8 a = *reinterpret_cast<const bf16x8*>(&sm.dpA[row16][kt * 32 + g * 8]);
        acc = __builtin_amdgcn_mfma_f32_16x16x32_bf16(a, fA[kt], acc, 0, 0, 0);
      }
      if (c < H_DIM) {
#pragma unroll
        for (int reg = 0; reg < 4; ++reg)
          sm.z_s[(g * 4 + reg) * H_DIM + c] = acc[reg];
      }
    } else if (next_s >= 0) {
      const uint32_t ka = sm.keyA[next_s], kb = sm.keyB[next_s];
#pragma unroll
      for (int rr = 0; rr < 2; ++rr) {
        const int r = (wave - 8) * 2 + rr;
#pragma unroll
        for (int itn = 0; itn < 2; ++itn) {
          const int h = lane + itn * 64;
          if (h < H_DIM) {
            const uint32_t f = (uint32_t)(blk * (ROWS * H_DIM) + r * H_DIM + h);
            uint32_t o0, o1;
            threefry2x32(ka, kb, 0u, f, o0, o1);
            const uint32_t bits = o0 ^ o1;
            const float fr = __uint_as_float((bits >> 9) | 0x3F800000u) - 1.0f;
            const float minv = -0.99999994f;  // nextafter(-1, 0)
            const float u = fmaxf(fr * 2.0f + minv, minv);
            const float n = 1.41421354f * erfinv_f32(u);
            sm.dw_s[r * H_DIM + h] = n * sqdt;
          }
        }
      }
    }
    __syncthreads();
  }

  for (int e = tid; e < ROWS * H_DIM; e += THREADS) {
    out_xfin[(size_t)row0 * H_DIM + e] = sm.x_s[e];
    out_zfin[(size_t)row0 * H_DIM + e] = sm.z_s[e];
  }
  if (tid < ROWS) out_yfin[row0 + tid] = sm.y_s[tid];
}

extern "C" void kernel_launch(void* const* d_in, const int* in_sizes, int n_in,
                              void* d_out, int out_size, void* d_ws, size_t ws_size,
                              hipStream_t stream) {
  (void)in_sizes; (void)n_in; (void)ws_size; (void)out_size;
  const float* x0 = (const float*)d_in[0];
  const float* t0 = (const float*)d_in[1];
  const float* dt = (const float*)d_in[2];
  const float* W0 = (const float*)d_in[4];
  const float* b0 = (const float*)d_in[5];
  const float* W1 = (const float*)d_in[6];
  const float* b1 = (const float*)d_in[7];
  const float* W2 = (const float*)d_in[8];
  const float* b2 = (const float*)d_in[9];
  const float* W3 = (const float*)d_in[10];
  const float* b3 = (const float*)d_in[11];
  const float* W4 = (const float*)d_in[12];
  const float* b4 = (const float*)d_in[13];
  uint16_t* P = (uint16_t*)d_ws;
  float* out = (float*)d_out;

  hipLaunchKernelGGL(pack_kernel, dim3(PACK_GRID), dim3(256), 0, stream,
                     W0, W1, W2, W3, W4, P);
  hipLaunchKernelGGL(fbsde_kernel, dim3(NBLK), dim3(THREADS), 0, stream,
                     x0, t0, dt, b0, b1, b2, b3, W4, b4, P, out);
}

// Round 8
// 4152.123 us; speedup vs baseline: 1.1690x; 1.1038x over previous
//
#include <hip/hip_runtime.h>
#include <stdint.h>

#define B_TRAJ  4096
#define H_DIM   100
#define T_STEPS 100
#define ROWS    16
#define NBLK    256
#define THREADS 1024

typedef float    f32x4  __attribute__((ext_vector_type(4)));
typedef __bf16   bf16x8 __attribute__((ext_vector_type(8)));
typedef uint16_t u16x8  __attribute__((ext_vector_type(8)));

// ---- packed-weight layout in d_ws (u16/bf16 elements) ----
// within a pack: idx = (kt*N + n)*32 + kk ; kk = g*8 + e maps k = kt*32+kk
#define OFF_P0F  0        // [4][256][32]  W0[n][k]  (K pad 128)
#define OFF_P1F  32768    // [8][256][32]  W1[n][k]
#define OFF_P2F  98304
#define OFF_P3F  163840
#define OFF_P1B  229376   // [8][256][32]  W1[k][n]
#define OFF_P2B  294912
#define OFF_P3B  360448
#define OFF_P0B  425984   // [8][128][32]  W0[k][1+n] (N pad 128)
#define OFF_W4P  458752   // [256] bf16 W4 linear
#define OFF_KEYS 459008   // 200 x u32 (as 400 u16 slots)
#define PACK_TOTAL 459008
#define PACK_GRID ((PACK_TOTAL + 255) / 256)

__device__ __forceinline__ uint16_t f2bf(float f) {
  uint32_t u = __float_as_uint(f);
  uint32_t r = u + 0x7FFFu + ((u >> 16) & 1u);   // RNE
  return (uint16_t)(r >> 16);
}
__device__ __forceinline__ float bf2f(uint16_t u) {
  return __uint_as_float(((uint32_t)u) << 16);
}
__device__ __forceinline__ uint32_t rotl32(uint32_t v, int d) {
  return (v << d) | (v >> (32 - d));
}

// JAX Threefry-2x32, 20 rounds, exact key schedule.
__device__ __forceinline__ void threefry2x32(uint32_t k0, uint32_t k1,
                                             uint32_t x0, uint32_t x1,
                                             uint32_t& o0, uint32_t& o1) {
  const uint32_t k2 = k0 ^ k1 ^ 0x1BD11BDAu;
  x0 += k0; x1 += k1;
  x0 += x1; x1 = rotl32(x1, 13); x1 ^= x0;
  x0 += x1; x1 = rotl32(x1, 15); x1 ^= x0;
  x0 += x1; x1 = rotl32(x1, 26); x1 ^= x0;
  x0 += x1; x1 = rotl32(x1,  6); x1 ^= x0;
  x0 += k1; x1 += k2 + 1u;
  x0 += x1; x1 = rotl32(x1, 17); x1 ^= x0;
  x0 += x1; x1 = rotl32(x1, 29); x1 ^= x0;
  x0 += x1; x1 = rotl32(x1, 16); x1 ^= x0;
  x0 += x1; x1 = rotl32(x1, 24); x1 ^= x0;
  x0 += k2; x1 += k0 + 2u;
  x0 += x1; x1 = rotl32(x1, 13); x1 ^= x0;
  x0 += x1; x1 = rotl32(x1, 15); x1 ^= x0;
  x0 += x1; x1 = rotl32(x1, 26); x1 ^= x0;
  x0 += x1; x1 = rotl32(x1,  6); x1 ^= x0;
  x0 += k0; x1 += k1 + 3u;
  x0 += x1; x1 = rotl32(x1, 17); x1 ^= x0;
  x0 += x1; x1 = rotl32(x1, 29); x1 ^= x0;
  x0 += x1; x1 = rotl32(x1, 16); x1 ^= x0;
  x0 += x1; x1 = rotl32(x1, 24); x1 ^= x0;
  x0 += k1; x1 += k2 + 4u;
  x0 += x1; x1 = rotl32(x1, 13); x1 ^= x0;
  x0 += x1; x1 = rotl32(x1, 15); x1 ^= x0;
  x0 += x1; x1 = rotl32(x1, 26); x1 ^= x0;
  x0 += x1; x1 = rotl32(x1,  6); x1 ^= x0;
  x0 += k2; x1 += k0 + 5u;
  o0 = x0; o1 = x1;
}

// XLA ErfInv32 (Giles)
__device__ __forceinline__ float erfinv_f32(float x) {
  float w = -log1pf(-x * x);
  float p;
  if (w < 5.0f) {
    w = w - 2.5f;
    p = 2.81022636e-08f;
    p = fmaf(p, w, 3.43273939e-07f);
    p = fmaf(p, w, -3.5233877e-06f);
    p = fmaf(p, w, -4.39150654e-06f);
    p = fmaf(p, w, 0.00021858087f);
    p = fmaf(p, w, -0.00125372503f);
    p = fmaf(p, w, -0.00417768164f);
    p = fmaf(p, w, 0.246640727f);
    p = fmaf(p, w, 1.50140941f);
  } else {
    w = sqrtf(w) - 3.0f;
    p = -0.000200214257f;
    p = fmaf(p, w, 0.000100950558f);
    p = fmaf(p, w, 0.00134934322f);
    p = fmaf(p, w, -0.00367342844f);
    p = fmaf(p, w, 0.00573950773f);
    p = fmaf(p, w, -0.0076224613f);
    p = fmaf(p, w, 0.00943887047f);
    p = fmaf(p, w, 1.00167406f);
    p = fmaf(p, w, 2.83297682f);
  }
  return p * x;
}

// ---------------- weight packing + key chain (once per launch) ----------------
__global__ __launch_bounds__(256) void pack_kernel(
    const float* __restrict__ W0, const float* __restrict__ W1,
    const float* __restrict__ W2, const float* __restrict__ W3,
    const float* __restrict__ W4, uint16_t* __restrict__ P) {
  const int i = blockIdx.x * 256 + threadIdx.x;
  if (i == 0) {  // serial key chain: key(42), per step use child0, carry child1
    uint32_t* K = (uint32_t*)(P + OFF_KEYS);
    uint32_t c0 = 0u, c1 = 42u;
    for (int s = 0; s < T_STEPS; ++s) {
      uint32_t a0_, a1_, n0, n1;
      threefry2x32(c0, c1, 0u, 0u, a0_, a1_);
      threefry2x32(c0, c1, 0u, 1u, n0, n1);
      K[2 * s] = a0_; K[2 * s + 1] = a1_;
      c0 = n0; c1 = n1;
    }
  }
  if (i >= PACK_TOTAL) return;
  float v;
  if (i < OFF_P1F) {                 // P0F
    int e = i - OFF_P0F;
    int kk = e & 31, n = (e >> 5) & 255, kt = e >> 13;
    int k = kt * 32 + kk;
    v = (k < 101) ? W0[n * 101 + k] : 0.0f;
  } else if (i < OFF_P2F) {          // P1F
    int e = i - OFF_P1F;
    int kk = e & 31, n = (e >> 5) & 255, kt = e >> 13;
    v = W1[n * 256 + kt * 32 + kk];
  } else if (i < OFF_P3F) {          // P2F
    int e = i - OFF_P2F;
    int kk = e & 31, n = (e >> 5) & 255, kt = e >> 13;
    v = W2[n * 256 + kt * 32 + kk];
  } else if (i < OFF_P1B) {          // P3F
    int e = i - OFF_P3F;
    int kk = e & 31, n = (e >> 5) & 255, kt = e >> 13;
    v = W3[n * 256 + kt * 32 + kk];
  } else if (i < OFF_P2B) {          // P1B
    int e = i - OFF_P1B;
    int kk = e & 31, n = (e >> 5) & 255, kt = e >> 13;
    v = W1[(kt * 32 + kk) * 256 + n];
  } else if (i < OFF_P3B) {          // P2B
    int e = i - OFF_P2B;
    int kk = e & 31, n = (e >> 5) & 255, kt = e >> 13;
    v = W2[(kt * 32 + kk) * 256 + n];
  } else if (i < OFF_P0B) {          // P3B
    int e = i - OFF_P3B;
    int kk = e & 31, n = (e >> 5) & 255, kt = e >> 13;
    v = W3[(kt * 32 + kk) * 256 + n];
  } else if (i < OFF_W4P) {          // P0B
    int e = i - OFF_P0B;
    int kk = e & 31, n = (e >> 5) & 127, kt = e >> 12;
    int k = kt * 32 + kk;
    v = (n < 100) ? W0[k * 101 + 1 + n] : 0.0f;
  } else {                           // W4P
    v = W4[i - OFF_W4P];
  }
  P[i] = f2bf(v);
}

// ---------------- LDS ----------------
struct SmemT {
  uint16_t actI[ROWS][136];   // MLP input, K padded to 128
  uint16_t act1[ROWS][264];
  uint16_t act2[ROWS][264];
  uint16_t act3[ROWS][264];
  uint16_t act4[ROWS][264];
  uint16_t dpA[ROWS][264];
  uint16_t dpB[ROWS][264];
  float x_s[ROWS * H_DIM];
  float z_s[ROWS * H_DIM];
  float dw_s[ROWS * H_DIM];
  float y_s[ROWS];
  uint32_t keyA[T_STEPS], keyB[T_STEPS];
};

// ---------------- GEMM phase bodies (MFMA 16x16x32 bf16) ----------------
// R3-proven JIT-load form: fragments loaded inside the phase, right before
// use. The compiler keeps ~2-3 in flight at 52 VGPR and everything hits L2.
// (R4-R7's persistent prefetch arrays forced scratch spill whose L2 pollution
// evicted the weight pack: FETCH 4.5MB -> 11GB. Do NOT reintroduce.)
// D[r][c]: r=(lane>>4)*4+reg, c=lane&15 (m89).  A[r][kslot]: r=lane&15.
// kslot=(g,e) packing identical on A and B, so HW k-permutation cancels.

template<int KT, int INS>
__device__ __forceinline__ void fwd_jit(const uint16_t (*in)[INS],
                                        const uint16_t* __restrict__ Pm,
                                        uint32_t voff,
                                        const float* __restrict__ bias,
                                        uint16_t (*outb)[264],
                                        int row16, int g, int c) {
  bf16x8 bfr[KT], afr[KT];
#pragma unroll
  for (int kt = 0; kt < KT; ++kt)
    bfr[kt] = *reinterpret_cast<const bf16x8*>(Pm + kt * 8192 + voff);
#pragma unroll
  for (int kt = 0; kt < KT; ++kt)
    afr[kt] = *reinterpret_cast<const bf16x8*>(&in[row16][kt * 32 + g * 8]);
  const float bv = bias[c];
  f32x4 acc = {bv, bv, bv, bv};
#pragma unroll
  for (int kt = 0; kt < KT; ++kt)
    acc = __builtin_amdgcn_mfma_f32_16x16x32_bf16(afr[kt], bfr[kt], acc, 0, 0, 0);
#pragma unroll
  for (int reg = 0; reg < 4; ++reg)
    outb[g * 4 + reg][c] = f2bf(fmaxf(acc[reg], 0.0f));
}

__device__ __forceinline__ void bwd_jit(const uint16_t (*in)[264],
                                        const uint16_t* __restrict__ Pm,
                                        uint32_t voff,
                                        const uint16_t (*mact)[264],
                                        uint16_t (*outb)[264],
                                        int row16, int g, int c) {
  bf16x8 bfr[8], afr[8];
#pragma unroll
  for (int kt = 0; kt < 8; ++kt)
    bfr[kt] = *reinterpret_cast<const bf16x8*>(Pm + kt * 8192 + voff);
#pragma unroll
  for (int kt = 0; kt < 8; ++kt)
    afr[kt] = *reinterpret_cast<const bf16x8*>(&in[row16][kt * 32 + g * 8]);
  f32x4 acc = {0.f, 0.f, 0.f, 0.f};
#pragma unroll
  for (int kt = 0; kt < 8; ++kt)
    acc = __builtin_amdgcn_mfma_f32_16x16x32_bf16(afr[kt], bfr[kt], acc, 0, 0, 0);
#pragma unroll
  for (int reg = 0; reg < 4; ++reg) {
    const int r = g * 4 + reg;
    outb[r][c] = mact[r][c] ? f2bf(acc[reg]) : (uint16_t)0;
  }
}

// ---------------- main kernel ----------------
__global__ __launch_bounds__(THREADS) void fbsde_kernel(
    const float* __restrict__ x0, const float* __restrict__ t0p,
    const float* __restrict__ dtp,
    const float* __restrict__ b0, const float* __restrict__ b1,
    const float* __restrict__ b2, const float* __restrict__ b3,
    const float* __restrict__ W4, const float* __restrict__ b4,
    const uint16_t* __restrict__ P, float* __restrict__ out) {
  __shared__ __align__(16) SmemT sm;

  const int tid = threadIdx.x;
  const int wave = tid >> 6, lane = tid & 63;
  const int row16 = lane & 15, g = lane >> 4;
  const int c = row16 + 16 * wave;
  const uint32_t voff = (uint32_t)(c * 32 + g * 8);   // fragment element offset
  const int blk = blockIdx.x;
  const int row0 = blk * ROWS;

  // ---- init ----
  if (tid < T_STEPS) {
    const uint32_t* K = (const uint32_t*)(P + OFF_KEYS);
    sm.keyA[tid] = K[2 * tid];
    sm.keyB[tid] = K[2 * tid + 1];
  }
  for (int e = tid; e < ROWS * H_DIM; e += THREADS)
    sm.x_s[e] = x0[row0 * H_DIM + e];
  for (int e = tid; e < ROWS * 136; e += THREADS) {
    const int r = e / 136, cc = e - r * 136;
    uint16_t v = 0;
    if (cc >= 1 && cc <= H_DIM) v = f2bf(x0[(row0 + r) * H_DIM + cc - 1]);
    sm.actI[r][cc] = v;   // cc==0 -> t=0.0 -> bf16 0
  }
  const float t0v = t0p[0];
  const float dtv = dtp[0];
  const float sqdt = sqrtf(dtv);
  __syncthreads();

  float* const out_xfin = out;                                  // (B,H)
  float* const out_yfin = out + 409600;                         // (B,1)
  float* const out_zfin = out + 413696;                         // (B,H)
  float* const out_xs   = out + 823296;                         // (T,B,H)
  float* const out_yt   = out + 823296 + 40960000;              // (T,B,1)
  float* const out_ys   = out + 823296 + 40960000 + 409600;     // (T,B,1)

  // it = 0: initial eval at t=0 (no SDE phase, no ys write, gen dW for step 0)
  // it>=1:  SDE phase for s=it-1, then eval (writes ys[s], gen dW for step it)
  for (int it = 0; it <= T_STEPS; ++it) {
    const int s = it - 1;

    if (it > 0) {
      // ---- SDE phase: y_tilde + x-update + next actI; wave w owns row w ----
      const float tv = t0v + (float)it * dtv;
      const int base = wave * H_DIM;
      const int h0 = lane;                 // < 100 always (lane<64)
      const int h1 = lane + 64;            // valid if < 100
      const float xv0 = sm.x_s[base + h0];
      const float zv0 = sm.z_s[base + h0];
      const float dw0 = sm.dw_s[base + h0];
      float s1 = xv0 * zv0;
      float s2 = zv0 * (0.4f * xv0) * dw0;
      float xv1 = 0.f, dw1 = 0.f;
      if (h1 < H_DIM) {
        xv1 = sm.x_s[base + h1];
        const float zv1 = sm.z_s[base + h1];
        dw1 = sm.dw_s[base + h1];
        s1 += xv1 * zv1;
        s2 += zv1 * (0.4f * xv1) * dw1;
      }
#pragma unroll
      for (int off = 32; off >= 1; off >>= 1) {
        s1 += __shfl_xor(s1, off, 64);
        s2 += __shfl_xor(s2, off, 64);
      }
      if (lane == 0) {
        const float yv = sm.y_s[wave];
        const float phi = 0.05f * (yv - s1);
        out_yt[(size_t)s * B_TRAJ + row0 + wave] = yv + phi * dtv + s2;
        sm.actI[wave][0] = f2bf(tv);
      }
      {
        const float x1 = xv0 + (0.4f * xv0) * dw0;
        sm.x_s[base + h0] = x1;
        sm.actI[wave][1 + h0] = f2bf(x1);
        out_xs[(size_t)s * (B_TRAJ * H_DIM) + (size_t)(row0 + wave) * H_DIM + h0] = x1;
        if (h1 < H_DIM) {
          const float x1b = xv1 + (0.4f * xv1) * dw1;
          sm.x_s[base + h1] = x1b;
          sm.actI[wave][1 + h1] = f2bf(x1b);
          out_xs[(size_t)s * (B_TRAJ * H_DIM) + (size_t)(row0 + wave) * H_DIM + h1] = x1b;
        }
      }
      __syncthreads();
    }

    // ======== MLP fwd + VJP eval ========
    float* const ys_out = (it > 0) ? (out_ys + (size_t)s * B_TRAJ) : nullptr;
    const int next_s = (it < T_STEPS) ? it : -1;

    // P0: fwd0 (K=128)
    fwd_jit<4, 136>(sm.actI, P + OFF_P0F, voff, b0, sm.act1, row16, g, c);
    __syncthreads();
    // P1-P3: fwd 256->256
    fwd_jit<8, 264>(sm.act1, P + OFF_P1F, voff, b1, sm.act2, row16, g, c);
    __syncthreads();
    fwd_jit<8, 264>(sm.act2, P + OFF_P2F, voff, b2, sm.act3, row16, g, c);
    __syncthreads();
    fwd_jit<8, 264>(sm.act3, P + OFF_P3F, voff, b3, sm.act4, row16, g, c);
    __syncthreads();

    // P4: y-reduce + bwd3 (dp4 built on the fly from act4 mask x W4)
    {
      float sy = 0.0f;
#pragma unroll
      for (int m = 0; m < 4; ++m) {
        const int j = lane + (m << 6);
        sy += bf2f(sm.act4[wave][j]) * W4[j];
      }
#pragma unroll
      for (int off = 32; off >= 1; off >>= 1) sy += __shfl_xor(sy, off, 64);
      if (lane == 0) {
        const float yv = sy + b4[0];
        sm.y_s[wave] = yv;
        if (ys_out) ys_out[row0 + wave] = yv;
      }
      const uint16_t* W4P = P + OFF_W4P;
      bf16x8 bfr[8], afr[8];
#pragma unroll
      for (int kt = 0; kt < 8; ++kt)
        bfr[kt] = *reinterpret_cast<const bf16x8*>(P + OFF_P3B + kt * 8192 + voff);
#pragma unroll
      for (int kt = 0; kt < 8; ++kt) {
        u16x8 au = *reinterpret_cast<const u16x8*>(&sm.act4[row16][kt * 32 + g * 8]);
        u16x8 wu = *reinterpret_cast<const u16x8*>(&W4P[kt * 32 + g * 8]);
        u16x8 sel;
#pragma unroll
        for (int e = 0; e < 8; ++e) sel[e] = au[e] ? wu[e] : (uint16_t)0;
        afr[kt] = __builtin_bit_cast(bf16x8, sel);
      }
      f32x4 acc = {0.f, 0.f, 0.f, 0.f};
#pragma unroll
      for (int kt = 0; kt < 8; ++kt)
        acc = __builtin_amdgcn_mfma_f32_16x16x32_bf16(afr[kt], bfr[kt], acc, 0, 0, 0);
#pragma unroll
      for (int reg = 0; reg < 4; ++reg) {
        const int r = g * 4 + reg;
        sm.dpA[r][c] = sm.act3[r][c] ? f2bf(acc[reg]) : (uint16_t)0;
      }
    }
    __syncthreads();

    // P5: bwd2 ; P6: bwd1
    bwd_jit(sm.dpA, P + OFF_P2B, voff, sm.act2, sm.dpB, row16, g, c);
    __syncthreads();
    bwd_jit(sm.dpB, P + OFF_P1B, voff, sm.act1, sm.dpA, row16, g, c);
    __syncthreads();

    // P7: bwd0 on waves 0-7 (z out, N=128 pack); waves 8-15 run next-step PRNG
    if (wave < 8) {
      bf16x8 bfr[8], afr[8];
#pragma unroll
      for (int kt = 0; kt < 8; ++kt)
        bfr[kt] = *reinterpret_cast<const bf16x8*>(P + OFF_P0B + kt * 4096 + voff);
#pragma unroll
      for (int kt = 0; kt < 8; ++kt)
        afr[kt] = *reinterpret_cast<const bf16x8*>(&sm.dpA[row16][kt * 32 + g * 8]);
      f32x4 acc = {0.f, 0.f, 0.f, 0.f};
#pragma unroll
      for (int kt = 0; kt < 8; ++kt)
        acc = __builtin_amdgcn_mfma_f32_16x16x32_bf16(afr[kt], bfr[kt], acc, 0, 0, 0);
      if (c < H_DIM) {
#pragma unroll
        for (int reg = 0; reg < 4; ++reg)
          sm.z_s[(g * 4 + reg) * H_DIM + c] = acc[reg];
      }
    } else if (next_s >= 0) {
      const uint32_t ka = sm.keyA[next_s], kb = sm.keyB[next_s];
#pragma unroll
      for (int rr = 0; rr < 2; ++rr) {
        const int r = (wave - 8) * 2 + rr;
#pragma unroll
        for (int itn = 0; itn < 2; ++itn) {
          const int h = lane + itn * 64;
          if (h < H_DIM) {
            const uint32_t f = (uint32_t)(blk * (ROWS * H_DIM) + r * H_DIM + h);
            uint32_t o0, o1;
            threefry2x32(ka, kb, 0u, f, o0, o1);
            const uint32_t bits = o0 ^ o1;
            const float fr = __uint_as_float((bits >> 9) | 0x3F800000u) - 1.0f;
            const float minv = -0.99999994f;  // nextafter(-1, 0)
            const float u = fmaxf(fr * 2.0f + minv, minv);
            const float n = 1.41421354f * erfinv_f32(u);
            sm.dw_s[r * H_DIM + h] = n * sqdt;
          }
        }
      }
    }
    __syncthreads();
  }

  for (int e = tid; e < ROWS * H_DIM; e += THREADS) {
    out_xfin[(size_t)row0 * H_DIM + e] = sm.x_s[e];
    out_zfin[(size_t)row0 * H_DIM + e] = sm.z_s[e];
  }
  if (tid < ROWS) out_yfin[row0 + tid] = sm.y_s[tid];
}

extern "C" void kernel_launch(void* const* d_in, const int* in_sizes, int n_in,
                              void* d_out, int out_size, void* d_ws, size_t ws_size,
                              hipStream_t stream) {
  (void)in_sizes; (void)n_in; (void)ws_size; (void)out_size;
  const float* x0 = (const float*)d_in[0];
  const float* t0 = (const float*)d_in[1];
  const float* dt = (const float*)d_in[2];
  const float* W0 = (const float*)d_in[4];
  const float* b0 = (const float*)d_in[5];
  const float* W1 = (const float*)d_in[6];
  const float* b1 = (const float*)d_in[7];
  const float* W2 = (const float*)d_in[8];
  const float* b2 = (const float*)d_in[9];
  const float* W3 = (const float*)d_in[10];
  const float* b3 = (const float*)d_in[11];
  const float* W4 = (const float*)d_in[12];
  const float* b4 = (const float*)d_in[13];
  uint16_t* P = (uint16_t*)d_ws;
  float* out = (float*)d_out;

  hipLaunchKernelGGL(pack_kernel, dim3(PACK_GRID), dim3(256), 0, stream,
                     W0, W1, W2, W3, W4, P);
  hipLaunchKernelGGL(fbsde_kernel, dim3(NBLK), dim3(THREADS), 0, stream,
                     x0, t0, dt, b0, b1, b2, b3, W4, b4, P, out);
}

// Round 9
// 1967.133 us; speedup vs baseline: 2.4674x; 2.1107x over previous
//
#include <hip/hip_runtime.h>
#include <stdint.h>

#define B_TRAJ  4096
#define H_DIM   100
#define T_STEPS 100
#define ROWS    16
#define NBLK    256
#define THREADS 1024

typedef float    f32x4  __attribute__((ext_vector_type(4)));
typedef __bf16   bf16x8 __attribute__((ext_vector_type(8)));
typedef uint16_t u16x8  __attribute__((ext_vector_type(8)));

// ---- packed-weight layout in d_ws (u16/bf16 elements) ----
// within a pack: idx = (kt*N + n)*32 + kk ; kk = g*8 + e maps k = kt*32+kk
#define OFF_P0F  0        // [4][256][32]  W0[n][k]  (K pad 128)
#define OFF_P1F  32768    // [8][256][32]  W1[n][k]
#define OFF_P2F  98304
#define OFF_P3F  163840
#define OFF_P1B  229376   // [8][256][32]  W1[k][n]
#define OFF_P2B  294912
#define OFF_P3B  360448
#define OFF_P0B  425984   // [8][128][32]  W0[k][1+n] (N pad 128)
#define OFF_W4P  458752   // [256] bf16 W4 linear
#define OFF_KEYS 459008   // 200 x u32 (as 400 u16 slots)
#define PACK_TOTAL 459008
#define PACK_GRID ((PACK_TOTAL + 255) / 256)

__device__ __forceinline__ uint16_t f2bf(float f) {
  uint32_t u = __float_as_uint(f);
  uint32_t r = u + 0x7FFFu + ((u >> 16) & 1u);   // RNE
  return (uint16_t)(r >> 16);
}
__device__ __forceinline__ float bf2f(uint16_t u) {
  return __uint_as_float(((uint32_t)u) << 16);
}
__device__ __forceinline__ uint32_t rotl32(uint32_t v, int d) {
  return (v << d) | (v >> (32 - d));
}

// JAX Threefry-2x32, 20 rounds, exact key schedule.
__device__ __forceinline__ void threefry2x32(uint32_t k0, uint32_t k1,
                                             uint32_t x0, uint32_t x1,
                                             uint32_t& o0, uint32_t& o1) {
  const uint32_t k2 = k0 ^ k1 ^ 0x1BD11BDAu;
  x0 += k0; x1 += k1;
  x0 += x1; x1 = rotl32(x1, 13); x1 ^= x0;
  x0 += x1; x1 = rotl32(x1, 15); x1 ^= x0;
  x0 += x1; x1 = rotl32(x1, 26); x1 ^= x0;
  x0 += x1; x1 = rotl32(x1,  6); x1 ^= x0;
  x0 += k1; x1 += k2 + 1u;
  x0 += x1; x1 = rotl32(x1, 17); x1 ^= x0;
  x0 += x1; x1 = rotl32(x1, 29); x1 ^= x0;
  x0 += x1; x1 = rotl32(x1, 16); x1 ^= x0;
  x0 += x1; x1 = rotl32(x1, 24); x1 ^= x0;
  x0 += k2; x1 += k0 + 2u;
  x0 += x1; x1 = rotl32(x1, 13); x1 ^= x0;
  x0 += x1; x1 = rotl32(x1, 15); x1 ^= x0;
  x0 += x1; x1 = rotl32(x1, 26); x1 ^= x0;
  x0 += x1; x1 = rotl32(x1,  6); x1 ^= x0;
  x0 += k0; x1 += k1 + 3u;
  x0 += x1; x1 = rotl32(x1, 17); x1 ^= x0;
  x0 += x1; x1 = rotl32(x1, 29); x1 ^= x0;
  x0 += x1; x1 = rotl32(x1, 16); x1 ^= x0;
  x0 += x1; x1 = rotl32(x1, 24); x1 ^= x0;
  x0 += k1; x1 += k2 + 4u;
  x0 += x1; x1 = rotl32(x1, 13); x1 ^= x0;
  x0 += x1; x1 = rotl32(x1, 15); x1 ^= x0;
  x0 += x1; x1 = rotl32(x1, 26); x1 ^= x0;
  x0 += x1; x1 = rotl32(x1,  6); x1 ^= x0;
  x0 += k2; x1 += k0 + 5u;
  o0 = x0; o1 = x1;
}

// XLA ErfInv32 (Giles)
__device__ __forceinline__ float erfinv_f32(float x) {
  float w = -log1pf(-x * x);
  float p;
  if (w < 5.0f) {
    w = w - 2.5f;
    p = 2.81022636e-08f;
    p = fmaf(p, w, 3.43273939e-07f);
    p = fmaf(p, w, -3.5233877e-06f);
    p = fmaf(p, w, -4.39150654e-06f);
    p = fmaf(p, w, 0.00021858087f);
    p = fmaf(p, w, -0.00125372503f);
    p = fmaf(p, w, -0.00417768164f);
    p = fmaf(p, w, 0.246640727f);
    p = fmaf(p, w, 1.50140941f);
  } else {
    w = sqrtf(w) - 3.0f;
    p = -0.000200214257f;
    p = fmaf(p, w, 0.000100950558f);
    p = fmaf(p, w, 0.00134934322f);
    p = fmaf(p, w, -0.00367342844f);
    p = fmaf(p, w, 0.00573950773f);
    p = fmaf(p, w, -0.0076224613f);
    p = fmaf(p, w, 0.00943887047f);
    p = fmaf(p, w, 1.00167406f);
    p = fmaf(p, w, 2.83297682f);
  }
  return p * x;
}

// ---------------- weight packing + key chain (once per launch) ----------------
__global__ __launch_bounds__(256) void pack_kernel(
    const float* __restrict__ W0, const float* __restrict__ W1,
    const float* __restrict__ W2, const float* __restrict__ W3,
    const float* __restrict__ W4, uint16_t* __restrict__ P) {
  const int i = blockIdx.x * 256 + threadIdx.x;
  if (i == 0) {  // serial key chain: key(42), per step use child0, carry child1
    uint32_t* K = (uint32_t*)(P + OFF_KEYS);
    uint32_t c0 = 0u, c1 = 42u;
    for (int s = 0; s < T_STEPS; ++s) {
      uint32_t a0_, a1_, n0, n1;
      threefry2x32(c0, c1, 0u, 0u, a0_, a1_);
      threefry2x32(c0, c1, 0u, 1u, n0, n1);
      K[2 * s] = a0_; K[2 * s + 1] = a1_;
      c0 = n0; c1 = n1;
    }
  }
  if (i >= PACK_TOTAL) return;
  float v;
  if (i < OFF_P1F) {                 // P0F
    int e = i - OFF_P0F;
    int kk = e & 31, n = (e >> 5) & 255, kt = e >> 13;
    int k = kt * 32 + kk;
    v = (k < 101) ? W0[n * 101 + k] : 0.0f;
  } else if (i < OFF_P2F) {          // P1F
    int e = i - OFF_P1F;
    int kk = e & 31, n = (e >> 5) & 255, kt = e >> 13;
    v = W1[n * 256 + kt * 32 + kk];
  } else if (i < OFF_P3F) {          // P2F
    int e = i - OFF_P2F;
    int kk = e & 31, n = (e >> 5) & 255, kt = e >> 13;
    v = W2[n * 256 + kt * 32 + kk];
  } else if (i < OFF_P1B) {          // P3F
    int e = i - OFF_P3F;
    int kk = e & 31, n = (e >> 5) & 255, kt = e >> 13;
    v = W3[n * 256 + kt * 32 + kk];
  } else if (i < OFF_P2B) {          // P1B
    int e = i - OFF_P1B;
    int kk = e & 31, n = (e >> 5) & 255, kt = e >> 13;
    v = W1[(kt * 32 + kk) * 256 + n];
  } else if (i < OFF_P3B) {          // P2B
    int e = i - OFF_P2B;
    int kk = e & 31, n = (e >> 5) & 255, kt = e >> 13;
    v = W2[(kt * 32 + kk) * 256 + n];
  } else if (i < OFF_P0B) {          // P3B
    int e = i - OFF_P3B;
    int kk = e & 31, n = (e >> 5) & 255, kt = e >> 13;
    v = W3[(kt * 32 + kk) * 256 + n];
  } else if (i < OFF_W4P) {          // P0B
    int e = i - OFF_P0B;
    int kk = e & 31, n = (e >> 5) & 127, kt = e >> 12;
    int k = kt * 32 + kk;
    v = (n < 100) ? W0[k * 101 + 1 + n] : 0.0f;
  } else {                           // W4P
    v = W4[i - OFF_W4P];
  }
  P[i] = f2bf(v);
}

// ---------------- LDS ----------------
struct SmemT {
  uint16_t actI[ROWS][136];   // MLP input, K padded to 128
  uint16_t act1[ROWS][264];
  uint16_t act2[ROWS][264];
  uint16_t act3[ROWS][264];
  uint16_t act4[ROWS][264];
  uint16_t dpA[ROWS][264];
  uint16_t dpB[ROWS][264];
  float x_s[ROWS * H_DIM];
  float z_s[ROWS * H_DIM];
  float dw_s[ROWS * H_DIM];
  float y_s[ROWS];
  uint32_t keyA[T_STEPS], keyB[T_STEPS];
};

// ---------------- GEMM phase helpers (MFMA 16x16x32 bf16, JIT loads) -------
// D[r][c]: r=(lane>>4)*4+reg, c=lane&15 (m89).  A[r][kslot]: r=lane&15.
// kslot=(g,e) packing identical on A and B, so HW k-permutation cancels.

template<int KT, int INS>
__device__ __forceinline__ void gemm_fwd(const uint16_t (*in)[INS],
                                         const uint16_t* __restrict__ P,
                                         const float* __restrict__ bias,
                                         uint16_t (*outb)[264],
                                         int wave, int lane) {
  const int row16 = lane & 15, g = lane >> 4;
  const int c = row16 + 16 * wave;
  bf16x8 bfr[KT], afr[KT];
#pragma unroll
  for (int kt = 0; kt < KT; ++kt)
    bfr[kt] = *reinterpret_cast<const bf16x8*>(&P[(kt * 256 + c) * 32 + g * 8]);
#pragma unroll
  for (int kt = 0; kt < KT; ++kt)
    afr[kt] = *reinterpret_cast<const bf16x8*>(&in[row16][kt * 32 + g * 8]);
  const float bv = bias[c];
  f32x4 acc = {bv, bv, bv, bv};
#pragma unroll
  for (int kt = 0; kt < KT; ++kt)
    acc = __builtin_amdgcn_mfma_f32_16x16x32_bf16(afr[kt], bfr[kt], acc, 0, 0, 0);
#pragma unroll
  for (int reg = 0; reg < 4; ++reg)
    outb[g * 4 + reg][c] = f2bf(fmaxf(acc[reg], 0.0f));
}

__device__ __forceinline__ void gemm_bwd(const uint16_t (*in)[264],
                                         const uint16_t* __restrict__ P,
                                         const uint16_t (*mact)[264],
                                         uint16_t (*outb)[264],
                                         int wave, int lane) {
  const int row16 = lane & 15, g = lane >> 4;
  const int c = row16 + 16 * wave;
  bf16x8 bfr[8], afr[8];
#pragma unroll
  for (int kt = 0; kt < 8; ++kt)
    bfr[kt] = *reinterpret_cast<const bf16x8*>(&P[(kt * 256 + c) * 32 + g * 8]);
#pragma unroll
  for (int kt = 0; kt < 8; ++kt)
    afr[kt] = *reinterpret_cast<const bf16x8*>(&in[row16][kt * 32 + g * 8]);
  f32x4 acc = {0.f, 0.f, 0.f, 0.f};
#pragma unroll
  for (int kt = 0; kt < 8; ++kt)
    acc = __builtin_amdgcn_mfma_f32_16x16x32_bf16(afr[kt], bfr[kt], acc, 0, 0, 0);
#pragma unroll
  for (int reg = 0; reg < 4; ++reg) {
    const int r = g * 4 + reg;
    outb[r][c] = mact[r][c] ? f2bf(acc[reg]) : (uint16_t)0;
  }
}

// bwd3 with on-the-fly dp4 = (act4!=0 ? W4 : 0); no dp4 LDS round trip.
__device__ __forceinline__ void gemm_bwd3(const uint16_t (*act4)[264],
                                          const uint16_t* __restrict__ P,
                                          const uint16_t* __restrict__ W4P,
                                          const uint16_t (*mact)[264],
                                          uint16_t (*outb)[264],
                                          int wave, int lane) {
  const int row16 = lane & 15, g = lane >> 4;
  const int c = row16 + 16 * wave;
  bf16x8 bfr[8], afr[8];
#pragma unroll
  for (int kt = 0; kt < 8; ++kt)
    bfr[kt] = *reinterpret_cast<const bf16x8*>(&P[(kt * 256 + c) * 32 + g * 8]);
#pragma unroll
  for (int kt = 0; kt < 8; ++kt) {
    u16x8 au = *reinterpret_cast<const u16x8*>(&act4[row16][kt * 32 + g * 8]);
    u16x8 wu = *reinterpret_cast<const u16x8*>(&W4P[kt * 32 + g * 8]);
    u16x8 sel;
#pragma unroll
    for (int e = 0; e < 8; ++e) sel[e] = au[e] ? wu[e] : (uint16_t)0;
    afr[kt] = __builtin_bit_cast(bf16x8, sel);
  }
  f32x4 acc = {0.f, 0.f, 0.f, 0.f};
#pragma unroll
  for (int kt = 0; kt < 8; ++kt)
    acc = __builtin_amdgcn_mfma_f32_16x16x32_bf16(afr[kt], bfr[kt], acc, 0, 0, 0);
#pragma unroll
  for (int reg = 0; reg < 4; ++reg) {
    const int r = g * 4 + reg;
    outb[r][c] = mact[r][c] ? f2bf(acc[reg]) : (uint16_t)0;
  }
}

// ---------------- MLP fwd + VJP eval (NOINLINE: hard codegen boundary) ------
// R3 (52 VGPR, FETCH 4.5 MB, 2157 us) had this as an outlined function; when
// the body was flattened inline (R7/R8) the scheduler hoisted weight loads
// across barriers, blew the 64-VGPR budget, and the scratch spill's L2
// pollution caused 10.5 GB of HBM weight re-fetch. Keep this NOINLINE.
__device__ __attribute__((noinline)) void mlp_eval(
    SmemT& sm, const uint16_t* __restrict__ P,
    const float* __restrict__ b0, const float* __restrict__ b1,
    const float* __restrict__ b2, const float* __restrict__ b3,
    const float* __restrict__ W4, const float* __restrict__ b4,
    float* __restrict__ ys_out, int row0, int next_s, int blk, float sqdt) {
  const int tid = threadIdx.x;
  const int wave = tid >> 6, lane = tid & 63;
  const int row16 = lane & 15, g = lane >> 4;

  // P0-P3: forward layers
  gemm_fwd<4, 136>(sm.actI, P + OFF_P0F, b0, sm.act1, wave, lane);
  __syncthreads();
  gemm_fwd<8, 264>(sm.act1, P + OFF_P1F, b1, sm.act2, wave, lane);
  __syncthreads();
  gemm_fwd<8, 264>(sm.act2, P + OFF_P2F, b2, sm.act3, wave, lane);
  __syncthreads();
  gemm_fwd<8, 264>(sm.act3, P + OFF_P3F, b3, sm.act4, wave, lane);
  __syncthreads();

  // P4: y-reduction (wave w owns row w) + bwd3 with on-the-fly dp4
  {
    float sy = 0.0f;
#pragma unroll
    for (int m = 0; m < 4; ++m) {
      const int j = lane + (m << 6);
      sy += bf2f(sm.act4[wave][j]) * W4[j];
    }
#pragma unroll
    for (int off = 32; off >= 1; off >>= 1) sy += __shfl_xor(sy, off, 64);
    if (lane == 0) {
      const float yv = sy + b4[0];
      sm.y_s[wave] = yv;
      if (ys_out) ys_out[row0 + wave] = yv;
    }
  }
  gemm_bwd3(sm.act4, P + OFF_P3B, P + OFF_W4P, sm.act3, sm.dpA, wave, lane);
  __syncthreads();

  // P5: bwd2 ; P6: bwd1
  gemm_bwd(sm.dpA, P + OFF_P2B, sm.act2, sm.dpB, wave, lane);
  __syncthreads();
  gemm_bwd(sm.dpB, P + OFF_P1B, sm.act1, sm.dpA, wave, lane);
  __syncthreads();

  // P7: bwd0 on waves 0-7 (z out, N=128 pack); waves 8-15 next-step PRNG
  if (wave < 8) {
    const int c = row16 + 16 * wave;   // < 128
    bf16x8 bfr[8], afr[8];
#pragma unroll
    for (int kt = 0; kt < 8; ++kt)
      bfr[kt] = *reinterpret_cast<const bf16x8*>(&P[OFF_P0B + (kt * 128 + c) * 32 + g * 8]);
#pragma unroll
    for (int kt = 0; kt < 8; ++kt)
      afr[kt] = *reinterpret_cast<const bf16x8*>(&sm.dpA[row16][kt * 32 + g * 8]);
    f32x4 acc = {0.f, 0.f, 0.f, 0.f};
#pragma unroll
    for (int kt = 0; kt < 8; ++kt)
      acc = __builtin_amdgcn_mfma_f32_16x16x32_bf16(afr[kt], bfr[kt], acc, 0, 0, 0);
    if (c < H_DIM) {
#pragma unroll
      for (int reg = 0; reg < 4; ++reg)
        sm.z_s[(g * 4 + reg) * H_DIM + c] = acc[reg];
    }
  } else if (next_s >= 0) {
    const uint32_t ka = sm.keyA[next_s], kb = sm.keyB[next_s];
#pragma unroll
    for (int rr = 0; rr < 2; ++rr) {
      const int r = (wave - 8) * 2 + rr;
#pragma unroll
      for (int itn = 0; itn < 2; ++itn) {
        const int h = lane + itn * 64;
        if (h < H_DIM) {
          const uint32_t f = (uint32_t)(blk * (ROWS * H_DIM) + r * H_DIM + h);
          uint32_t o0, o1;
          threefry2x32(ka, kb, 0u, f, o0, o1);
          const uint32_t bits = o0 ^ o1;
          const float fr = __uint_as_float((bits >> 9) | 0x3F800000u) - 1.0f;
          const float minv = -0.99999994f;  // nextafter(-1, 0)
          const float u = fmaxf(fr * 2.0f + minv, minv);
          const float n = 1.41421354f * erfinv_f32(u);
          sm.dw_s[r * H_DIM + h] = n * sqdt;
        }
      }
    }
  }
  __syncthreads();
}

// ---------------- main kernel ----------------
__global__ __launch_bounds__(THREADS, 4) void fbsde_kernel(
    const float* __restrict__ x0, const float* __restrict__ t0p,
    const float* __restrict__ dtp,
    const float* __restrict__ b0, const float* __restrict__ b1,
    const float* __restrict__ b2, const float* __restrict__ b3,
    const float* __restrict__ W4, const float* __restrict__ b4,
    const uint16_t* __restrict__ P, float* __restrict__ out) {
  __shared__ __align__(16) SmemT sm;

  const int tid = threadIdx.x;
  const int wave = tid >> 6, lane = tid & 63;
  const int blk = blockIdx.x;
  const int row0 = blk * ROWS;

  // ---- init ----
  if (tid < T_STEPS) {
    const uint32_t* K = (const uint32_t*)(P + OFF_KEYS);
    sm.keyA[tid] = K[2 * tid];
    sm.keyB[tid] = K[2 * tid + 1];
  }
  for (int e = tid; e < ROWS * H_DIM; e += THREADS)
    sm.x_s[e] = x0[row0 * H_DIM + e];
  for (int e = tid; e < ROWS * 136; e += THREADS) {
    const int r = e / 136, cc = e - r * 136;
    uint16_t v = 0;
    if (cc >= 1 && cc <= H_DIM) v = f2bf(x0[(row0 + r) * H_DIM + cc - 1]);
    sm.actI[r][cc] = v;   // cc==0 -> t=0.0 -> bf16 0
  }
  const float t0v = t0p[0];
  const float dtv = dtp[0];
  const float sqdt = sqrtf(dtv);
  __syncthreads();

  float* const out_xfin = out;                                  // (B,H)
  float* const out_yfin = out + 409600;                         // (B,1)
  float* const out_zfin = out + 413696;                         // (B,H)
  float* const out_xs   = out + 823296;                         // (T,B,H)
  float* const out_yt   = out + 823296 + 40960000;              // (T,B,1)
  float* const out_ys   = out + 823296 + 40960000 + 409600;     // (T,B,1)

  // initial eval at t=0 (no ys write; waves 8-15 generate dW for step 0)
  mlp_eval(sm, P, b0, b1, b2, b3, W4, b4, nullptr, row0, 0, blk, sqdt);

  for (int s = 0; s < T_STEPS; ++s) {
    // ---- SDE phase: y_tilde + x-update + next actI; wave w owns row w ----
    const float tv = t0v + (float)(s + 1) * dtv;
    {
      const int base = wave * H_DIM;
      const int h0 = lane;                 // < 100 always (lane<64)
      const int h1 = lane + 64;            // valid if < 100
      const float xv0 = sm.x_s[base + h0];
      const float zv0 = sm.z_s[base + h0];
      const float dw0 = sm.dw_s[base + h0];
      float s1 = xv0 * zv0;
      float s2 = zv0 * (0.4f * xv0) * dw0;
      float xv1 = 0.f, dw1 = 0.f;
      if (h1 < H_DIM) {
        xv1 = sm.x_s[base + h1];
        const float zv1 = sm.z_s[base + h1];
        dw1 = sm.dw_s[base + h1];
        s1 += xv1 * zv1;
        s2 += zv1 * (0.4f * xv1) * dw1;
      }
#pragma unroll
      for (int off = 32; off >= 1; off >>= 1) {
        s1 += __shfl_xor(s1, off, 64);
        s2 += __shfl_xor(s2, off, 64);
      }
      if (lane == 0) {
        const float yv = sm.y_s[wave];
        const float phi = 0.05f * (yv - s1);
        out_yt[(size_t)s * B_TRAJ + row0 + wave] = yv + phi * dtv + s2;
        sm.actI[wave][0] = f2bf(tv);
      }
      {
        const float x1 = xv0 + (0.4f * xv0) * dw0;
        sm.x_s[base + h0] = x1;
        sm.actI[wave][1 + h0] = f2bf(x1);
        out_xs[(size_t)s * (B_TRAJ * H_DIM) + (size_t)(row0 + wave) * H_DIM + h0] = x1;
        if (h1 < H_DIM) {
          const float x1b = xv1 + (0.4f * xv1) * dw1;
          sm.x_s[base + h1] = x1b;
          sm.actI[wave][1 + h1] = f2bf(x1b);
          out_xs[(size_t)s * (B_TRAJ * H_DIM) + (size_t)(row0 + wave) * H_DIM + h1] = x1b;
        }
      }
    }
    __syncthreads();

    mlp_eval(sm, P, b0, b1, b2, b3, W4, b4, out_ys + (size_t)s * B_TRAJ,
             row0, (s + 1 < T_STEPS) ? s + 1 : -1, blk, sqdt);
  }

  for (int e = tid; e < ROWS * H_DIM; e += THREADS) {
    out_xfin[(size_t)row0 * H_DIM + e] = sm.x_s[e];
    out_zfin[(size_t)row0 * H_DIM + e] = sm.z_s[e];
  }
  if (tid < ROWS) out_yfin[row0 + tid] = sm.y_s[tid];
}

extern "C" void kernel_launch(void* const* d_in, const int* in_sizes, int n_in,
                              void* d_out, int out_size, void* d_ws, size_t ws_size,
                              hipStream_t stream) {
  (void)in_sizes; (void)n_in; (void)ws_size; (void)out_size;
  const float* x0 = (const float*)d_in[0];
  const float* t0 = (const float*)d_in[1];
  const float* dt = (const float*)d_in[2];
  const float* W0 = (const float*)d_in[4];
  const float* b0 = (const float*)d_in[5];
  const float* W1 = (const float*)d_in[6];
  const float* b1 = (const float*)d_in[7];
  const float* W2 = (const float*)d_in[8];
  const float* b2 = (const float*)d_in[9];
  const float* W3 = (const float*)d_in[10];
  const float* b3 = (const float*)d_in[11];
  const float* W4 = (const float*)d_in[12];
  const float* b4 = (const float*)d_in[13];
  uint16_t* P = (uint16_t*)d_ws;
  float* out = (float*)d_out;

  hipLaunchKernelGGL(pack_kernel, dim3(PACK_GRID), dim3(256), 0, stream,
                     W0, W1, W2, W3, W4, P);
  hipLaunchKernelGGL(fbsde_kernel, dim3(NBLK), dim3(THREADS), 0, stream,
                     x0, t0, dt, b0, b1, b2, b3, W4, b4, P, out);
}

// Round 10
// 1535.340 us; speedup vs baseline: 3.1613x; 1.2812x over previous
//
#include <hip/hip_runtime.h>
#include <stdint.h>

#define B_TRAJ  4096
#define H_DIM   100
#define T_STEPS 100
#define ROWS    16
#define NBLK    256
#define THREADS 1024

typedef float    f32x4  __attribute__((ext_vector_type(4)));
typedef __bf16   bf16x8 __attribute__((ext_vector_type(8)));
typedef uint16_t u16x8  __attribute__((ext_vector_type(8)));
typedef uint8_t  u8x8   __attribute__((ext_vector_type(8)));

// ---- packed-weight layout in d_ws (BYTE offsets) ----
// P0F (bf16): [4][256][32] u16 ; fp8 packs: [8][N][32] bytes, idx=(kt*N+n)*32+kk
// weights scaled x32 (W4 for dp4 x128); dp carried at 128x; z = acc/4096.
#define OB_P0F   0         // u16, 65536 B
#define OB_P1F   65536     // fp8 W1^T
#define OB_P2F   131072
#define OB_P3F   196608
#define OB_P1B   262144    // fp8 W1
#define OB_P2B   327680
#define OB_P3B   393216
#define OB_P0B   458752    // fp8 W0 cols, [8][128][32], 32768 B
#define OB_W4F8  491520    // fp8 W4 x128, 256 B
#define OB_KEYS  491776    // u32[200]
#define PACK_TOTAL 459008  // element-threads: 32768 u16 + 393216 + 32768 + 256
#define PACK_GRID ((PACK_TOTAL + 255) / 256)

#define WSCALE   32.0f
#define INV_WS   0.03125f        // 1/32
#define INV_ZS   2.44140625e-4f  // 1/4096

__device__ __forceinline__ uint16_t f2bf(float f) {
  uint32_t u = __float_as_uint(f);
  uint32_t r = u + 0x7FFFu + ((u >> 16) & 1u);   // RNE
  return (uint16_t)(r >> 16);
}
__device__ __forceinline__ float bf2f(uint16_t u) {
  return __uint_as_float(((uint32_t)u) << 16);
}
__device__ __forceinline__ uint8_t f2e4m3(float v) {
  int pk = __builtin_amdgcn_cvt_pk_fp8_f32(v, 0.0f, 0, false);
  return (uint8_t)(pk & 0xFF);
}
__device__ __forceinline__ uint32_t rotl32(uint32_t v, int d) {
  return (v << d) | (v >> (32 - d));
}

// JAX Threefry-2x32, 20 rounds, exact key schedule.
__device__ __forceinline__ void threefry2x32(uint32_t k0, uint32_t k1,
                                             uint32_t x0, uint32_t x1,
                                             uint32_t& o0, uint32_t& o1) {
  const uint32_t k2 = k0 ^ k1 ^ 0x1BD11BDAu;
  x0 += k0; x1 += k1;
  x0 += x1; x1 = rotl32(x1, 13); x1 ^= x0;
  x0 += x1; x1 = rotl32(x1, 15); x1 ^= x0;
  x0 += x1; x1 = rotl32(x1, 26); x1 ^= x0;
  x0 += x1; x1 = rotl32(x1,  6); x1 ^= x0;
  x0 += k1; x1 += k2 + 1u;
  x0 += x1; x1 = rotl32(x1, 17); x1 ^= x0;
  x0 += x1; x1 = rotl32(x1, 29); x1 ^= x0;
  x0 += x1; x1 = rotl32(x1, 16); x1 ^= x0;
  x0 += x1; x1 = rotl32(x1, 24); x1 ^= x0;
  x0 += k2; x1 += k0 + 2u;
  x0 += x1; x1 = rotl32(x1, 13); x1 ^= x0;
  x0 += x1; x1 = rotl32(x1, 15); x1 ^= x0;
  x0 += x1; x1 = rotl32(x1, 26); x1 ^= x0;
  x0 += x1; x1 = rotl32(x1,  6); x1 ^= x0;
  x0 += k0; x1 += k1 + 3u;
  x0 += x1; x1 = rotl32(x1, 17); x1 ^= x0;
  x0 += x1; x1 = rotl32(x1, 29); x1 ^= x0;
  x0 += x1; x1 = rotl32(x1, 16); x1 ^= x0;
  x0 += x1; x1 = rotl32(x1, 24); x1 ^= x0;
  x0 += k1; x1 += k2 + 4u;
  x0 += x1; x1 = rotl32(x1, 13); x1 ^= x0;
  x0 += x1; x1 = rotl32(x1, 15); x1 ^= x0;
  x0 += x1; x1 = rotl32(x1, 26); x1 ^= x0;
  x0 += x1; x1 = rotl32(x1,  6); x1 ^= x0;
  x0 += k2; x1 += k0 + 5u;
  o0 = x0; o1 = x1;
}

// XLA ErfInv32 (Giles)
__device__ __forceinline__ float erfinv_f32(float x) {
  float w = -log1pf(-x * x);
  float p;
  if (w < 5.0f) {
    w = w - 2.5f;
    p = 2.81022636e-08f;
    p = fmaf(p, w, 3.43273939e-07f);
    p = fmaf(p, w, -3.5233877e-06f);
    p = fmaf(p, w, -4.39150654e-06f);
    p = fmaf(p, w, 0.00021858087f);
    p = fmaf(p, w, -0.00125372503f);
    p = fmaf(p, w, -0.00417768164f);
    p = fmaf(p, w, 0.246640727f);
    p = fmaf(p, w, 1.50140941f);
  } else {
    w = sqrtf(w) - 3.0f;
    p = -0.000200214257f;
    p = fmaf(p, w, 0.000100950558f);
    p = fmaf(p, w, 0.00134934322f);
    p = fmaf(p, w, -0.00367342844f);
    p = fmaf(p, w, 0.00573950773f);
    p = fmaf(p, w, -0.0076224613f);
    p = fmaf(p, w, 0.00943887047f);
    p = fmaf(p, w, 1.00167406f);
    p = fmaf(p, w, 2.83297682f);
  }
  return p * x;
}

// ---------------- weight packing + key chain (once per launch) ----------------
__global__ __launch_bounds__(256) void pack_kernel(
    const float* __restrict__ W0, const float* __restrict__ W1,
    const float* __restrict__ W2, const float* __restrict__ W3,
    const float* __restrict__ W4, uint8_t* __restrict__ P) {
  const int i = blockIdx.x * 256 + threadIdx.x;
  if (i == 0) {  // serial key chain: key(42), per step use child0, carry child1
    uint32_t* K = (uint32_t*)(P + OB_KEYS);
    uint32_t c0 = 0u, c1 = 42u;
    for (int s = 0; s < T_STEPS; ++s) {
      uint32_t a0_, a1_, n0, n1;
      threefry2x32(c0, c1, 0u, 0u, a0_, a1_);
      threefry2x32(c0, c1, 0u, 1u, n0, n1);
      K[2 * s] = a0_; K[2 * s + 1] = a1_;
      c0 = n0; c1 = n1;
    }
  }
  if (i >= PACK_TOTAL) return;

  if (i < 32768) {                  // P0F bf16: [4][256][32], W0[n][k], K pad 128
    const int e = i;
    const int kk = e & 31, n = (e >> 5) & 255, kt = e >> 13;
    const int k = kt * 32 + kk;
    const float v = (k < 101) ? W0[n * 101 + k] : 0.0f;
    ((uint16_t*)(P + OB_P0F))[e] = f2bf(v);
    return;
  }
  int j = i - 32768;
  if (j < 393216) {                 // six fp8 packs, x32
    const int pk = j >> 16;         // 0..5
    const int e = j & 65535;
    const int kk = e & 31, n = (e >> 5) & 255, kt = e >> 13;
    const int k = kt * 32 + kk;
    float v;
    switch (pk) {
      case 0: v = W1[n * 256 + k]; break;           // P1F = W1^T
      case 1: v = W2[n * 256 + k]; break;
      case 2: v = W3[n * 256 + k]; break;
      case 3: v = W1[k * 256 + n]; break;           // P1B = W1
      case 4: v = W2[k * 256 + n]; break;
      default: v = W3[k * 256 + n]; break;
    }
    P[OB_P1F + j] = f2e4m3(v * WSCALE);
    return;
  }
  j -= 393216;
  if (j < 32768) {                  // P0B fp8: [8][128][32], W0[k][1+n], x32
    const int kk = j & 31, n = (j >> 5) & 127, kt = j >> 12;
    const int k = kt * 32 + kk;
    const float v = (n < 100) ? W0[k * 101 + 1 + n] : 0.0f;
    P[OB_P0B + j] = f2e4m3(v * WSCALE);
    return;
  }
  j -= 32768;                       // W4 fp8 x128 (dp4 scale)
  P[OB_W4F8 + j] = f2e4m3(W4[j] * 128.0f);
}

// ---------------- LDS ----------------
struct SmemT {
  uint16_t actI[ROWS][136];   // MLP input bf16, K padded to 128
  uint8_t  act1[ROWS][264];   // fp8 activations (scale 1)
  uint8_t  act2[ROWS][264];
  uint8_t  act3[ROWS][264];
  uint8_t  act4[ROWS][264];
  uint8_t  dpA[ROWS][264];    // fp8 dp (scale 128)
  uint8_t  dpB[ROWS][264];
  float x_s[ROWS * H_DIM];
  float z_s[ROWS * H_DIM];
  float dw_s[ROWS * H_DIM];
  float y_s[ROWS];
  uint32_t keyA[T_STEPS], keyB[T_STEPS];
};

// ---------------- fp8 GEMM phase helpers (MFMA 16x16x32 fp8_fp8) ----------
// Same (g,e) k-slot packing on A and B -> HW k-permutation cancels (as bf16).
// D[r][c]: r=(lane>>4)*4+reg, c=lane&15.

__device__ __forceinline__ void gemm_fwd_f8(const uint8_t (*in)[264],
                                            const uint8_t* __restrict__ Pm,
                                            const float* __restrict__ bias,
                                            uint8_t (*outb)[264],
                                            int wave, int lane) {
  const int row16 = lane & 15, g = lane >> 4;
  const int c = row16 + 16 * wave;
  long bfr[8], afr[8];
#pragma unroll
  for (int kt = 0; kt < 8; ++kt)
    bfr[kt] = *reinterpret_cast<const long*>(Pm + (kt * 256 + c) * 32 + g * 8);
#pragma unroll
  for (int kt = 0; kt < 8; ++kt)
    afr[kt] = *reinterpret_cast<const long*>(&in[row16][kt * 32 + g * 8]);
  f32x4 acc = {0.f, 0.f, 0.f, 0.f};
#pragma unroll
  for (int kt = 0; kt < 8; ++kt)
    acc = __builtin_amdgcn_mfma_f32_16x16x32_fp8_fp8(afr[kt], bfr[kt], acc, 0, 0, 0);
  const float bv = bias[c];
  const float h0 = fmaxf(fmaf(acc[0], INV_WS, bv), 0.0f);
  const float h1 = fmaxf(fmaf(acc[1], INV_WS, bv), 0.0f);
  const float h2 = fmaxf(fmaf(acc[2], INV_WS, bv), 0.0f);
  const float h3 = fmaxf(fmaf(acc[3], INV_WS, bv), 0.0f);
  const int p01 = __builtin_amdgcn_cvt_pk_fp8_f32(h0, h1, 0, false);
  const int p23 = __builtin_amdgcn_cvt_pk_fp8_f32(h2, h3, 0, false);
  outb[g * 4 + 0][c] = (uint8_t)(p01 & 0xFF);
  outb[g * 4 + 1][c] = (uint8_t)((p01 >> 8) & 0xFF);
  outb[g * 4 + 2][c] = (uint8_t)(p23 & 0xFF);
  outb[g * 4 + 3][c] = (uint8_t)((p23 >> 8) & 0xFF);
}

__device__ __forceinline__ void gemm_bwd_f8(const uint8_t (*in)[264],
                                            const uint8_t* __restrict__ Pm,
                                            const uint8_t (*mact)[264],
                                            uint8_t (*outb)[264],
                                            int wave, int lane) {
  const int row16 = lane & 15, g = lane >> 4;
  const int c = row16 + 16 * wave;
  long bfr[8], afr[8];
#pragma unroll
  for (int kt = 0; kt < 8; ++kt)
    bfr[kt] = *reinterpret_cast<const long*>(Pm + (kt * 256 + c) * 32 + g * 8);
#pragma unroll
  for (int kt = 0; kt < 8; ++kt)
    afr[kt] = *reinterpret_cast<const long*>(&in[row16][kt * 32 + g * 8]);
  f32x4 acc = {0.f, 0.f, 0.f, 0.f};
#pragma unroll
  for (int kt = 0; kt < 8; ++kt)
    acc = __builtin_amdgcn_mfma_f32_16x16x32_fp8_fp8(afr[kt], bfr[kt], acc, 0, 0, 0);
  // acc = 4096*dp_new ; store fp8 at dp scale 128 -> acc/32
  const int p01 = __builtin_amdgcn_cvt_pk_fp8_f32(acc[0] * INV_WS, acc[1] * INV_WS, 0, false);
  const int p23 = __builtin_amdgcn_cvt_pk_fp8_f32(acc[2] * INV_WS, acc[3] * INV_WS, 0, false);
  outb[g * 4 + 0][c] = mact[g * 4 + 0][c] ? (uint8_t)(p01 & 0xFF) : (uint8_t)0;
  outb[g * 4 + 1][c] = mact[g * 4 + 1][c] ? (uint8_t)((p01 >> 8) & 0xFF) : (uint8_t)0;
  outb[g * 4 + 2][c] = mact[g * 4 + 2][c] ? (uint8_t)(p23 & 0xFF) : (uint8_t)0;
  outb[g * 4 + 3][c] = mact[g * 4 + 3][c] ? (uint8_t)((p23 >> 8) & 0xFF) : (uint8_t)0;
}

// ---------------- MLP fwd + VJP eval (NOINLINE: hard codegen boundary) ------
// R9-proven: keep this outlined. Inlining it lets the scheduler hoist weight
// loads across barriers -> VGPR blowout -> scratch spill -> L2 pollution ->
// 10.5 GB HBM re-fetch (R7/R8). DO NOT inline.
__device__ __attribute__((noinline)) void mlp_eval(
    SmemT& sm, const uint8_t* __restrict__ P,
    const float* __restrict__ b0, const float* __restrict__ b1,
    const float* __restrict__ b2, const float* __restrict__ b3,
    const float* __restrict__ W4, const float* __restrict__ b4,
    float* __restrict__ ys_out, int row0, int next_s, int blk, float sqdt) {
  const int tid = threadIdx.x;
  const int wave = tid >> 6, lane = tid & 63;
  const int row16 = lane & 15, g = lane >> 4;
  const int c = row16 + 16 * wave;

  // P0: L0 fwd, bf16 MFMA (x-sensitivity: keep input layer high precision)
  {
    const uint16_t* P0F = (const uint16_t*)(P + OB_P0F);
    bf16x8 bfr[4], afr[4];
#pragma unroll
    for (int kt = 0; kt < 4; ++kt)
      bfr[kt] = *reinterpret_cast<const bf16x8*>(&P0F[(kt * 256 + c) * 32 + g * 8]);
#pragma unroll
    for (int kt = 0; kt < 4; ++kt)
      afr[kt] = *reinterpret_cast<const bf16x8*>(&sm.actI[row16][kt * 32 + g * 8]);
    const float bv = b0[c];
    f32x4 acc = {bv, bv, bv, bv};
#pragma unroll
    for (int kt = 0; kt < 4; ++kt)
      acc = __builtin_amdgcn_mfma_f32_16x16x32_bf16(afr[kt], bfr[kt], acc, 0, 0, 0);
    const float h0 = fmaxf(acc[0], 0.0f), h1 = fmaxf(acc[1], 0.0f);
    const float h2 = fmaxf(acc[2], 0.0f), h3 = fmaxf(acc[3], 0.0f);
    const int p01 = __builtin_amdgcn_cvt_pk_fp8_f32(h0, h1, 0, false);
    const int p23 = __builtin_amdgcn_cvt_pk_fp8_f32(h2, h3, 0, false);
    sm.act1[g * 4 + 0][c] = (uint8_t)(p01 & 0xFF);
    sm.act1[g * 4 + 1][c] = (uint8_t)((p01 >> 8) & 0xFF);
    sm.act1[g * 4 + 2][c] = (uint8_t)(p23 & 0xFF);
    sm.act1[g * 4 + 3][c] = (uint8_t)((p23 >> 8) & 0xFF);
  }
  __syncthreads();

  // P1-P3: fwd fp8
  gemm_fwd_f8(sm.act1, P + OB_P1F, b1, sm.act2, wave, lane);
  __syncthreads();
  gemm_fwd_f8(sm.act2, P + OB_P2F, b2, sm.act3, wave, lane);
  __syncthreads();
  gemm_fwd_f8(sm.act3, P + OB_P3F, b3, sm.act4, wave, lane);
  __syncthreads();

  // P4: y-reduction (wave w owns row w; act4 is fp8) + bwd3 with on-the-fly dp4
  {
    const uint32_t aw = *reinterpret_cast<const uint32_t*>(&sm.act4[wave][lane * 4]);
    float sy = __builtin_amdgcn_cvt_f32_fp8(aw, 0) * W4[lane * 4 + 0]
             + __builtin_amdgcn_cvt_f32_fp8(aw, 1) * W4[lane * 4 + 1]
             + __builtin_amdgcn_cvt_f32_fp8(aw, 2) * W4[lane * 4 + 2]
             + __builtin_amdgcn_cvt_f32_fp8(aw, 3) * W4[lane * 4 + 3];
#pragma unroll
    for (int off = 32; off >= 1; off >>= 1) sy += __shfl_xor(sy, off, 64);
    if (lane == 0) {
      const float yv = sy + b4[0];
      sm.y_s[wave] = yv;
      if (ys_out) ys_out[row0 + wave] = yv;
    }
  }
  {
    // dp4 (scale 128) = act4!=0 ? W4f8(x128) : 0 ; B = P3B (x32)
    const uint8_t* W4F8 = P + OB_W4F8;
    const uint8_t* Pm = P + OB_P3B;
    long bfr[8], afr[8];
#pragma unroll
    for (int kt = 0; kt < 8; ++kt)
      bfr[kt] = *reinterpret_cast<const long*>(Pm + (kt * 256 + c) * 32 + g * 8);
#pragma unroll
    for (int kt = 0; kt < 8; ++kt) {
      u8x8 au = *reinterpret_cast<const u8x8*>(&sm.act4[row16][kt * 32 + g * 8]);
      u8x8 wu = *reinterpret_cast<const u8x8*>(&W4F8[kt * 32 + g * 8]);
      u8x8 sel;
#pragma unroll
      for (int e = 0; e < 8; ++e) sel[e] = au[e] ? wu[e] : (uint8_t)0;
      afr[kt] = __builtin_bit_cast(long, sel);
    }
    f32x4 acc = {0.f, 0.f, 0.f, 0.f};
#pragma unroll
    for (int kt = 0; kt < 8; ++kt)
      acc = __builtin_amdgcn_mfma_f32_16x16x32_fp8_fp8(afr[kt], bfr[kt], acc, 0, 0, 0);
    const int p01 = __builtin_amdgcn_cvt_pk_fp8_f32(acc[0] * INV_WS, acc[1] * INV_WS, 0, false);
    const int p23 = __builtin_amdgcn_cvt_pk_fp8_f32(acc[2] * INV_WS, acc[3] * INV_WS, 0, false);
    sm.dpA[g * 4 + 0][c] = sm.act3[g * 4 + 0][c] ? (uint8_t)(p01 & 0xFF) : (uint8_t)0;
    sm.dpA[g * 4 + 1][c] = sm.act3[g * 4 + 1][c] ? (uint8_t)((p01 >> 8) & 0xFF) : (uint8_t)0;
    sm.dpA[g * 4 + 2][c] = sm.act3[g * 4 + 2][c] ? (uint8_t)(p23 & 0xFF) : (uint8_t)0;
    sm.dpA[g * 4 + 3][c] = sm.act3[g * 4 + 3][c] ? (uint8_t)((p23 >> 8) & 0xFF) : (uint8_t)0;
  }
  __syncthreads();

  // P5: bwd2 ; P6: bwd1 (fp8)
  gemm_bwd_f8(sm.dpA, P + OB_P2B, sm.act2, sm.dpB, wave, lane);
  __syncthreads();
  gemm_bwd_f8(sm.dpB, P + OB_P1B, sm.act1, sm.dpA, wave, lane);
  __syncthreads();

  // P7: bwd0 on waves 0-7 (z = acc/4096); waves 8-15 next-step PRNG
  if (wave < 8) {
    const uint8_t* Pm = P + OB_P0B;
    long bfr[8], afr[8];
#pragma unroll
    for (int kt = 0; kt < 8; ++kt)
      bfr[kt] = *reinterpret_cast<const long*>(Pm + (kt * 128 + c) * 32 + g * 8);
#pragma unroll
    for (int kt = 0; kt < 8; ++kt)
      afr[kt] = *reinterpret_cast<const long*>(&sm.dpA[row16][kt * 32 + g * 8]);
    f32x4 acc = {0.f, 0.f, 0.f, 0.f};
#pragma unroll
    for (int kt = 0; kt < 8; ++kt)
      acc = __builtin_amdgcn_mfma_f32_16x16x32_fp8_fp8(afr[kt], bfr[kt], acc, 0, 0, 0);
    if (c < H_DIM) {
#pragma unroll
      for (int reg = 0; reg < 4; ++reg)
        sm.z_s[(g * 4 + reg) * H_DIM + c] = acc[reg] * INV_ZS;
    }
  } else if (next_s >= 0) {
    const uint32_t ka = sm.keyA[next_s], kb = sm.keyB[next_s];
#pragma unroll
    for (int rr = 0; rr < 2; ++rr) {
      const int r = (wave - 8) * 2 + rr;
#pragma unroll
      for (int itn = 0; itn < 2; ++itn) {
        const int h = lane + itn * 64;
        if (h < H_DIM) {
          const uint32_t f = (uint32_t)(blk * (ROWS * H_DIM) + r * H_DIM + h);
          uint32_t o0, o1;
          threefry2x32(ka, kb, 0u, f, o0, o1);
          const uint32_t bits = o0 ^ o1;
          const float fr = __uint_as_float((bits >> 9) | 0x3F800000u) - 1.0f;
          const float minv = -0.99999994f;  // nextafter(-1, 0)
          const float u = fmaxf(fr * 2.0f + minv, minv);
          const float n = 1.41421354f * erfinv_f32(u);
          sm.dw_s[r * H_DIM + h] = n * sqdt;
        }
      }
    }
  }
  __syncthreads();
}

// ---------------- main kernel ----------------
__global__ __launch_bounds__(THREADS, 4) void fbsde_kernel(
    const float* __restrict__ x0, const float* __restrict__ t0p,
    const float* __restrict__ dtp,
    const float* __restrict__ b0, const float* __restrict__ b1,
    const float* __restrict__ b2, const float* __restrict__ b3,
    const float* __restrict__ W4, const float* __restrict__ b4,
    const uint8_t* __restrict__ P, float* __restrict__ out) {
  __shared__ __align__(16) SmemT sm;

  const int tid = threadIdx.x;
  const int wave = tid >> 6, lane = tid & 63;
  const int blk = blockIdx.x;
  const int row0 = blk * ROWS;

  // ---- init ----
  if (tid < T_STEPS) {
    const uint32_t* K = (const uint32_t*)(P + OB_KEYS);
    sm.keyA[tid] = K[2 * tid];
    sm.keyB[tid] = K[2 * tid + 1];
  }
  for (int e = tid; e < ROWS * H_DIM; e += THREADS)
    sm.x_s[e] = x0[row0 * H_DIM + e];
  for (int e = tid; e < ROWS * 136; e += THREADS) {
    const int r = e / 136, cc = e - r * 136;
    uint16_t v = 0;
    if (cc >= 1 && cc <= H_DIM) v = f2bf(x0[(row0 + r) * H_DIM + cc - 1]);
    sm.actI[r][cc] = v;   // cc==0 -> t=0.0 -> bf16 0
  }
  const float t0v = t0p[0];
  const float dtv = dtp[0];
  const float sqdt = sqrtf(dtv);
  __syncthreads();

  float* const out_xfin = out;                                  // (B,H)
  float* const out_yfin = out + 409600;                         // (B,1)
  float* const out_zfin = out + 413696;                         // (B,H)
  float* const out_xs   = out + 823296;                         // (T,B,H)
  float* const out_yt   = out + 823296 + 40960000;              // (T,B,1)
  float* const out_ys   = out + 823296 + 40960000 + 409600;     // (T,B,1)

  // initial eval at t=0 (no ys write; waves 8-15 generate dW for step 0)
  mlp_eval(sm, P, b0, b1, b2, b3, W4, b4, nullptr, row0, 0, blk, sqdt);

  for (int s = 0; s < T_STEPS; ++s) {
    // ---- SDE phase: y_tilde + x-update + next actI; wave w owns row w ----
    const float tv = t0v + (float)(s + 1) * dtv;
    {
      const int base = wave * H_DIM;
      const int h0 = lane;                 // < 100 always (lane<64)
      const int h1 = lane + 64;            // valid if < 100
      const float xv0 = sm.x_s[base + h0];
      const float zv0 = sm.z_s[base + h0];
      const float dw0 = sm.dw_s[base + h0];
      float s1 = xv0 * zv0;
      float s2 = zv0 * (0.4f * xv0) * dw0;
      float xv1 = 0.f, dw1 = 0.f;
      if (h1 < H_DIM) {
        xv1 = sm.x_s[base + h1];
        const float zv1 = sm.z_s[base + h1];
        dw1 = sm.dw_s[base + h1];
        s1 += xv1 * zv1;
        s2 += zv1 * (0.4f * xv1) * dw1;
      }
#pragma unroll
      for (int off = 32; off >= 1; off >>= 1) {
        s1 += __shfl_xor(s1, off, 64);
        s2 += __shfl_xor(s2, off, 64);
      }
      if (lane == 0) {
        const float yv = sm.y_s[wave];
        const float phi = 0.05f * (yv - s1);
        out_yt[(size_t)s * B_TRAJ + row0 + wave] = yv + phi * dtv + s2;
        sm.actI[wave][0] = f2bf(tv);
      }
      {
        const float x1 = xv0 + (0.4f * xv0) * dw0;
        sm.x_s[base + h0] = x1;
        sm.actI[wave][1 + h0] = f2bf(x1);
        out_xs[(size_t)s * (B_TRAJ * H_DIM) + (size_t)(row0 + wave) * H_DIM + h0] = x1;
        if (h1 < H_DIM) {
          const float x1b = xv1 + (0.4f * xv1) * dw1;
          sm.x_s[base + h1] = x1b;
          sm.actI[wave][1 + h1] = f2bf(x1b);
          out_xs[(size_t)s * (B_TRAJ * H_DIM) + (size_t)(row0 + wave) * H_DIM + h1] = x1b;
        }
      }
    }
    __syncthreads();

    mlp_eval(sm, P, b0, b1, b2, b3, W4, b4, out_ys + (size_t)s * B_TRAJ,
             row0, (s + 1 < T_STEPS) ? s + 1 : -1, blk, sqdt);
  }

  for (int e = tid; e < ROWS * H_DIM; e += THREADS) {
    out_xfin[(size_t)row0 * H_DIM + e] = sm.x_s[e];
    out_zfin[(size_t)row0 * H_DIM + e] = sm.z_s[e];
  }
  if (tid < ROWS) out_yfin[row0 + tid] = sm.y_s[tid];
}

extern "C" void kernel_launch(void* const* d_in, const int* in_sizes, int n_in,
                              void* d_out, int out_size, void* d_ws, size_t ws_size,
                              hipStream_t stream) {
  (void)in_sizes; (void)n_in; (void)ws_size; (void)out_size;
  const float* x0 = (const float*)d_in[0];
  const float* t0 = (const float*)d_in[1];
  const float* dt = (const float*)d_in[2];
  const float* W0 = (const float*)d_in[4];
  const float* b0 = (const float*)d_in[5];
  const float* W1 = (const float*)d_in[6];
  const float* b1 = (const float*)d_in[7];
  const float* W2 = (const float*)d_in[8];
  const float* b2 = (const float*)d_in[9];
  const float* W3 = (const float*)d_in[10];
  const float* b3 = (const float*)d_in[11];
  const float* W4 = (const float*)d_in[12];
  const float* b4 = (const float*)d_in[13];
  uint8_t* P = (uint8_t*)d_ws;
  float* out = (float*)d_out;

  hipLaunchKernelGGL(pack_kernel, dim3(PACK_GRID), dim3(256), 0, stream,
                     W0, W1, W2, W3, W4, P);
  hipLaunchKernelGGL(fbsde_kernel, dim3(NBLK), dim3(THREADS), 0, stream,
                     x0, t0, dt, b0, b1, b2, b3, W4, b4, P, out);
}

// Round 11
// 1212.189 us; speedup vs baseline: 4.0041x; 1.2666x over previous
//
#include <hip/hip_runtime.h>
#include <stdint.h>

#define B_TRAJ  4096
#define H_DIM   100
#define T_STEPS 100
#define ROWS    16
#define NBLK    256
#define THREADS 1024

typedef float    f32x4  __attribute__((ext_vector_type(4)));
typedef __bf16   bf16x8 __attribute__((ext_vector_type(8)));
typedef uint16_t u16x8  __attribute__((ext_vector_type(8)));
typedef uint8_t  u8x8   __attribute__((ext_vector_type(8)));

// ---- packed-weight layout in d_ws (BYTE offsets) ----
// P0F (bf16): [4][256][32] u16 ; fp8 packs: [8][N][32] bytes, idx=(kt*N+n)*32+kk
// weights scaled x32 (W4 for dp4 x128); dp carried at 128x; z = acc/4096.
#define OB_P0F   0         // u16, 65536 B
#define OB_P1F   65536     // fp8 W1^T
#define OB_P2F   131072
#define OB_P3F   196608
#define OB_P1B   262144    // fp8 W1
#define OB_P2B   327680
#define OB_P3B   393216
#define OB_P0B   458752    // fp8 W0 cols, [8][128][32], 32768 B
#define OB_W4F8  491520    // fp8 W4 x128, 256 B
#define OB_KEYS  491776    // u32[200]
#define PACK_TOTAL 459008  // element-threads: 32768 u16 + 393216 + 32768 + 256
#define PACK_GRID ((PACK_TOTAL + 255) / 256)

#define WSCALE   32.0f
#define INV_WS   0.03125f        // 1/32
#define INV_ZS   2.44140625e-4f  // 1/4096

__device__ __forceinline__ uint16_t f2bf(float f) {
  uint32_t u = __float_as_uint(f);
  uint32_t r = u + 0x7FFFu + ((u >> 16) & 1u);   // RNE
  return (uint16_t)(r >> 16);
}
__device__ __forceinline__ float bf2f(uint16_t u) {
  return __uint_as_float(((uint32_t)u) << 16);
}
__device__ __forceinline__ uint8_t f2e4m3(float v) {
  int pk = __builtin_amdgcn_cvt_pk_fp8_f32(v, 0.0f, 0, false);
  return (uint8_t)(pk & 0xFF);
}
__device__ __forceinline__ uint32_t rotl32(uint32_t v, int d) {
  return (v << d) | (v >> (32 - d));
}

// JAX Threefry-2x32, 20 rounds, exact key schedule.
__device__ __forceinline__ void threefry2x32(uint32_t k0, uint32_t k1,
                                             uint32_t x0, uint32_t x1,
                                             uint32_t& o0, uint32_t& o1) {
  const uint32_t k2 = k0 ^ k1 ^ 0x1BD11BDAu;
  x0 += k0; x1 += k1;
  x0 += x1; x1 = rotl32(x1, 13); x1 ^= x0;
  x0 += x1; x1 = rotl32(x1, 15); x1 ^= x0;
  x0 += x1; x1 = rotl32(x1, 26); x1 ^= x0;
  x0 += x1; x1 = rotl32(x1,  6); x1 ^= x0;
  x0 += k1; x1 += k2 + 1u;
  x0 += x1; x1 = rotl32(x1, 17); x1 ^= x0;
  x0 += x1; x1 = rotl32(x1, 29); x1 ^= x0;
  x0 += x1; x1 = rotl32(x1, 16); x1 ^= x0;
  x0 += x1; x1 = rotl32(x1, 24); x1 ^= x0;
  x0 += k2; x1 += k0 + 2u;
  x0 += x1; x1 = rotl32(x1, 13); x1 ^= x0;
  x0 += x1; x1 = rotl32(x1, 15); x1 ^= x0;
  x0 += x1; x1 = rotl32(x1, 26); x1 ^= x0;
  x0 += x1; x1 = rotl32(x1,  6); x1 ^= x0;
  x0 += k0; x1 += k1 + 3u;
  x0 += x1; x1 = rotl32(x1, 17); x1 ^= x0;
  x0 += x1; x1 = rotl32(x1, 29); x1 ^= x0;
  x0 += x1; x1 = rotl32(x1, 16); x1 ^= x0;
  x0 += x1; x1 = rotl32(x1, 24); x1 ^= x0;
  x0 += k1; x1 += k2 + 4u;
  x0 += x1; x1 = rotl32(x1, 13); x1 ^= x0;
  x0 += x1; x1 = rotl32(x1, 15); x1 ^= x0;
  x0 += x1; x1 = rotl32(x1, 26); x1 ^= x0;
  x0 += x1; x1 = rotl32(x1,  6); x1 ^= x0;
  x0 += k2; x1 += k0 + 5u;
  o0 = x0; o1 = x1;
}

// XLA ErfInv32 (Giles); w via fast hardware log (v_log_f32).
// w = -log(1 - x^2): fmaf(-x,x,1) preserves the cancellation structure;
// __logf ~1 ulp => dW perturbation ~1e-6 rel, negligible vs 0.124 threshold.
__device__ __forceinline__ float erfinv_f32(float x) {
  float w = -__logf(fmaf(-x, x, 1.0f));
  float p;
  if (w < 5.0f) {
    w = w - 2.5f;
    p = 2.81022636e-08f;
    p = fmaf(p, w, 3.43273939e-07f);
    p = fmaf(p, w, -3.5233877e-06f);
    p = fmaf(p, w, -4.39150654e-06f);
    p = fmaf(p, w, 0.00021858087f);
    p = fmaf(p, w, -0.00125372503f);
    p = fmaf(p, w, -0.00417768164f);
    p = fmaf(p, w, 0.246640727f);
    p = fmaf(p, w, 1.50140941f);
  } else {
    w = sqrtf(w) - 3.0f;
    p = -0.000200214257f;
    p = fmaf(p, w, 0.000100950558f);
    p = fmaf(p, w, 0.00134934322f);
    p = fmaf(p, w, -0.00367342844f);
    p = fmaf(p, w, 0.00573950773f);
    p = fmaf(p, w, -0.0076224613f);
    p = fmaf(p, w, 0.00943887047f);
    p = fmaf(p, w, 1.00167406f);
    p = fmaf(p, w, 2.83297682f);
  }
  return p * x;
}

// ---------------- weight packing + key chain (once per launch) ----------------
__global__ __launch_bounds__(256) void pack_kernel(
    const float* __restrict__ W0, const float* __restrict__ W1,
    const float* __restrict__ W2, const float* __restrict__ W3,
    const float* __restrict__ W4, uint8_t* __restrict__ P) {
  const int i = blockIdx.x * 256 + threadIdx.x;
  if (i == 0) {  // serial key chain: key(42), per step use child0, carry child1
    uint32_t* K = (uint32_t*)(P + OB_KEYS);
    uint32_t c0 = 0u, c1 = 42u;
    for (int s = 0; s < T_STEPS; ++s) {
      uint32_t a0_, a1_, n0, n1;
      threefry2x32(c0, c1, 0u, 0u, a0_, a1_);
      threefry2x32(c0, c1, 0u, 1u, n0, n1);
      K[2 * s] = a0_; K[2 * s + 1] = a1_;
      c0 = n0; c1 = n1;
    }
  }
  if (i >= PACK_TOTAL) return;

  if (i < 32768) {                  // P0F bf16: [4][256][32], W0[n][k], K pad 128
    const int e = i;
    const int kk = e & 31, n = (e >> 5) & 255, kt = e >> 13;
    const int k = kt * 32 + kk;
    const float v = (k < 101) ? W0[n * 101 + k] : 0.0f;
    ((uint16_t*)(P + OB_P0F))[e] = f2bf(v);
    return;
  }
  int j = i - 32768;
  if (j < 393216) {                 // six fp8 packs, x32
    const int pk = j >> 16;         // 0..5
    const int e = j & 65535;
    const int kk = e & 31, n = (e >> 5) & 255, kt = e >> 13;
    const int k = kt * 32 + kk;
    float v;
    switch (pk) {
      case 0: v = W1[n * 256 + k]; break;           // P1F = W1^T
      case 1: v = W2[n * 256 + k]; break;
      case 2: v = W3[n * 256 + k]; break;
      case 3: v = W1[k * 256 + n]; break;           // P1B = W1
      case 4: v = W2[k * 256 + n]; break;
      default: v = W3[k * 256 + n]; break;
    }
    P[OB_P1F + j] = f2e4m3(v * WSCALE);
    return;
  }
  j -= 393216;
  if (j < 32768) {                  // P0B fp8: [8][128][32], W0[k][1+n], x32
    const int kk = j & 31, n = (j >> 5) & 127, kt = j >> 12;
    const int k = kt * 32 + kk;
    const float v = (n < 100) ? W0[k * 101 + 1 + n] : 0.0f;
    P[OB_P0B + j] = f2e4m3(v * WSCALE);
    return;
  }
  j -= 32768;                       // W4 fp8 x128 (dp4 scale)
  P[OB_W4F8 + j] = f2e4m3(W4[j] * 128.0f);
}

// ---------------- LDS ----------------
struct SmemT {
  uint16_t actI[ROWS][136];   // MLP input bf16, K padded to 128
  uint8_t  act1[ROWS][264];   // fp8 activations (scale 1)
  uint8_t  act2[ROWS][264];
  uint8_t  act3[ROWS][264];
  uint8_t  act4[ROWS][264];
  uint8_t  dp4[ROWS][264];    // fp8 dp4 (scale 128), built in P3 epilogue
  uint8_t  dpA[ROWS][264];    // fp8 dp (scale 128)
  uint8_t  dpB[ROWS][264];
  float x_s[ROWS * H_DIM];
  float z_s[ROWS * H_DIM];
  float dw_s[ROWS * H_DIM];
  float y_s[ROWS];
  uint32_t keyA[T_STEPS], keyB[T_STEPS];
};

// ---------------- fp8 GEMM phase helpers (MFMA 16x16x32 fp8_fp8) ----------
// Same (g,e) k-slot packing on A and B -> HW k-permutation cancels (as bf16).
// D[r][c]: r=(lane>>4)*4+reg, c=lane&15.

__device__ __forceinline__ void gemm_fwd_f8(const uint8_t (*in)[264],
                                            const uint8_t* __restrict__ Pm,
                                            const float* __restrict__ bias,
                                            uint8_t (*outb)[264],
                                            int wave, int lane) {
  const int row16 = lane & 15, g = lane >> 4;
  const int c = row16 + 16 * wave;
  long bfr[8], afr[8];
#pragma unroll
  for (int kt = 0; kt < 8; ++kt)
    bfr[kt] = *reinterpret_cast<const long*>(Pm + (kt * 256 + c) * 32 + g * 8);
#pragma unroll
  for (int kt = 0; kt < 8; ++kt)
    afr[kt] = *reinterpret_cast<const long*>(&in[row16][kt * 32 + g * 8]);
  f32x4 acc = {0.f, 0.f, 0.f, 0.f};
#pragma unroll
  for (int kt = 0; kt < 8; ++kt)
    acc = __builtin_amdgcn_mfma_f32_16x16x32_fp8_fp8(afr[kt], bfr[kt], acc, 0, 0, 0);
  const float bv = bias[c];
  const float h0 = fmaxf(fmaf(acc[0], INV_WS, bv), 0.0f);
  const float h1 = fmaxf(fmaf(acc[1], INV_WS, bv), 0.0f);
  const float h2 = fmaxf(fmaf(acc[2], INV_WS, bv), 0.0f);
  const float h3 = fmaxf(fmaf(acc[3], INV_WS, bv), 0.0f);
  const int p01 = __builtin_amdgcn_cvt_pk_fp8_f32(h0, h1, 0, false);
  const int p23 = __builtin_amdgcn_cvt_pk_fp8_f32(h2, h3, 0, false);
  outb[g * 4 + 0][c] = (uint8_t)(p01 & 0xFF);
  outb[g * 4 + 1][c] = (uint8_t)((p01 >> 8) & 0xFF);
  outb[g * 4 + 2][c] = (uint8_t)(p23 & 0xFF);
  outb[g * 4 + 3][c] = (uint8_t)((p23 >> 8) & 0xFF);
}

// P3 variant: also emits dp4[r][c] = (act4>0 ? W4f8[c] : 0) from registers,
// replacing P4's 64-cndmask select build (R10 hotspot).
__device__ __forceinline__ void gemm_fwd3_f8(const uint8_t (*in)[264],
                                             const uint8_t* __restrict__ Pm,
                                             const float* __restrict__ bias,
                                             const uint8_t* __restrict__ W4F8,
                                             uint8_t (*outb)[264],
                                             uint8_t (*dp4b)[264],
                                             int wave, int lane) {
  const int row16 = lane & 15, g = lane >> 4;
  const int c = row16 + 16 * wave;
  long bfr[8], afr[8];
#pragma unroll
  for (int kt = 0; kt < 8; ++kt)
    bfr[kt] = *reinterpret_cast<const long*>(Pm + (kt * 256 + c) * 32 + g * 8);
#pragma unroll
  for (int kt = 0; kt < 8; ++kt)
    afr[kt] = *reinterpret_cast<const long*>(&in[row16][kt * 32 + g * 8]);
  f32x4 acc = {0.f, 0.f, 0.f, 0.f};
#pragma unroll
  for (int kt = 0; kt < 8; ++kt)
    acc = __builtin_amdgcn_mfma_f32_16x16x32_fp8_fp8(afr[kt], bfr[kt], acc, 0, 0, 0);
  const float bv = bias[c];
  const uint8_t w4b = W4F8[c];
  const float h0 = fmaxf(fmaf(acc[0], INV_WS, bv), 0.0f);
  const float h1 = fmaxf(fmaf(acc[1], INV_WS, bv), 0.0f);
  const float h2 = fmaxf(fmaf(acc[2], INV_WS, bv), 0.0f);
  const float h3 = fmaxf(fmaf(acc[3], INV_WS, bv), 0.0f);
  const int p01 = __builtin_amdgcn_cvt_pk_fp8_f32(h0, h1, 0, false);
  const int p23 = __builtin_amdgcn_cvt_pk_fp8_f32(h2, h3, 0, false);
  outb[g * 4 + 0][c] = (uint8_t)(p01 & 0xFF);
  outb[g * 4 + 1][c] = (uint8_t)((p01 >> 8) & 0xFF);
  outb[g * 4 + 2][c] = (uint8_t)(p23 & 0xFF);
  outb[g * 4 + 3][c] = (uint8_t)((p23 >> 8) & 0xFF);
  dp4b[g * 4 + 0][c] = (h0 > 0.0f) ? w4b : (uint8_t)0;
  dp4b[g * 4 + 1][c] = (h1 > 0.0f) ? w4b : (uint8_t)0;
  dp4b[g * 4 + 2][c] = (h2 > 0.0f) ? w4b : (uint8_t)0;
  dp4b[g * 4 + 3][c] = (h3 > 0.0f) ? w4b : (uint8_t)0;
}

__device__ __forceinline__ void gemm_bwd_f8(const uint8_t (*in)[264],
                                            const uint8_t* __restrict__ Pm,
                                            const uint8_t (*mact)[264],
                                            uint8_t (*outb)[264],
                                            int wave, int lane) {
  const int row16 = lane & 15, g = lane >> 4;
  const int c = row16 + 16 * wave;
  long bfr[8], afr[8];
#pragma unroll
  for (int kt = 0; kt < 8; ++kt)
    bfr[kt] = *reinterpret_cast<const long*>(Pm + (kt * 256 + c) * 32 + g * 8);
#pragma unroll
  for (int kt = 0; kt < 8; ++kt)
    afr[kt] = *reinterpret_cast<const long*>(&in[row16][kt * 32 + g * 8]);
  f32x4 acc = {0.f, 0.f, 0.f, 0.f};
#pragma unroll
  for (int kt = 0; kt < 8; ++kt)
    acc = __builtin_amdgcn_mfma_f32_16x16x32_fp8_fp8(afr[kt], bfr[kt], acc, 0, 0, 0);
  // acc = 4096*dp_new ; store fp8 at dp scale 128 -> acc/32
  const int p01 = __builtin_amdgcn_cvt_pk_fp8_f32(acc[0] * INV_WS, acc[1] * INV_WS, 0, false);
  const int p23 = __builtin_amdgcn_cvt_pk_fp8_f32(acc[2] * INV_WS, acc[3] * INV_WS, 0, false);
  outb[g * 4 + 0][c] = mact[g * 4 + 0][c] ? (uint8_t)(p01 & 0xFF) : (uint8_t)0;
  outb[g * 4 + 1][c] = mact[g * 4 + 1][c] ? (uint8_t)((p01 >> 8) & 0xFF) : (uint8_t)0;
  outb[g * 4 + 2][c] = mact[g * 4 + 2][c] ? (uint8_t)(p23 & 0xFF) : (uint8_t)0;
  outb[g * 4 + 3][c] = mact[g * 4 + 3][c] ? (uint8_t)((p23 >> 8) & 0xFF) : (uint8_t)0;
}

// ---------------- MLP fwd + VJP eval (NOINLINE: hard codegen boundary) ------
// R9-proven: keep this outlined. Inlining it lets the scheduler hoist weight
// loads across barriers -> VGPR blowout -> scratch spill -> L2 pollution ->
// 10.5 GB HBM re-fetch (R7/R8). DO NOT inline.
__device__ __attribute__((noinline)) void mlp_eval(
    SmemT& sm, const uint8_t* __restrict__ P,
    const float* __restrict__ b0, const float* __restrict__ b1,
    const float* __restrict__ b2, const float* __restrict__ b3,
    const float* __restrict__ W4, const float* __restrict__ b4,
    float* __restrict__ ys_out, int row0, int next_s, int blk, float sqdt) {
  const int tid = threadIdx.x;
  const int wave = tid >> 6, lane = tid & 63;
  const int row16 = lane & 15, g = lane >> 4;
  const int c = row16 + 16 * wave;

  // P0: L0 fwd, bf16 MFMA (x-sensitivity: keep input layer high precision)
  {
    const uint16_t* P0F = (const uint16_t*)(P + OB_P0F);
    bf16x8 bfr[4], afr[4];
#pragma unroll
    for (int kt = 0; kt < 4; ++kt)
      bfr[kt] = *reinterpret_cast<const bf16x8*>(&P0F[(kt * 256 + c) * 32 + g * 8]);
#pragma unroll
    for (int kt = 0; kt < 4; ++kt)
      afr[kt] = *reinterpret_cast<const bf16x8*>(&sm.actI[row16][kt * 32 + g * 8]);
    const float bv = b0[c];
    f32x4 acc = {bv, bv, bv, bv};
#pragma unroll
    for (int kt = 0; kt < 4; ++kt)
      acc = __builtin_amdgcn_mfma_f32_16x16x32_bf16(afr[kt], bfr[kt], acc, 0, 0, 0);
    const float h0 = fmaxf(acc[0], 0.0f), h1 = fmaxf(acc[1], 0.0f);
    const float h2 = fmaxf(acc[2], 0.0f), h3 = fmaxf(acc[3], 0.0f);
    const int p01 = __builtin_amdgcn_cvt_pk_fp8_f32(h0, h1, 0, false);
    const int p23 = __builtin_amdgcn_cvt_pk_fp8_f32(h2, h3, 0, false);
    sm.act1[g * 4 + 0][c] = (uint8_t)(p01 & 0xFF);
    sm.act1[g * 4 + 1][c] = (uint8_t)((p01 >> 8) & 0xFF);
    sm.act1[g * 4 + 2][c] = (uint8_t)(p23 & 0xFF);
    sm.act1[g * 4 + 3][c] = (uint8_t)((p23 >> 8) & 0xFF);
  }
  __syncthreads();

  // P1-P3: fwd fp8 (P3 also emits dp4 from registers)
  gemm_fwd_f8(sm.act1, P + OB_P1F, b1, sm.act2, wave, lane);
  __syncthreads();
  gemm_fwd_f8(sm.act2, P + OB_P2F, b2, sm.act3, wave, lane);
  __syncthreads();
  gemm_fwd3_f8(sm.act3, P + OB_P3F, b3, P + OB_W4F8, sm.act4, sm.dp4, wave, lane);
  __syncthreads();

  // P4: y-reduction (wave w owns row w; act4 is fp8) + bwd3 (A = dp4 tile)
  {
    const uint32_t aw = *reinterpret_cast<const uint32_t*>(&sm.act4[wave][lane * 4]);
    float sy = __builtin_amdgcn_cvt_f32_fp8(aw, 0) * W4[lane * 4 + 0]
             + __builtin_amdgcn_cvt_f32_fp8(aw, 1) * W4[lane * 4 + 1]
             + __builtin_amdgcn_cvt_f32_fp8(aw, 2) * W4[lane * 4 + 2]
             + __builtin_amdgcn_cvt_f32_fp8(aw, 3) * W4[lane * 4 + 3];
#pragma unroll
    for (int off = 32; off >= 1; off >>= 1) sy += __shfl_xor(sy, off, 64);
    if (lane == 0) {
      const float yv = sy + b4[0];
      sm.y_s[wave] = yv;
      if (ys_out) ys_out[row0 + wave] = yv;
    }
  }
  gemm_bwd_f8(sm.dp4, P + OB_P3B, sm.act3, sm.dpA, wave, lane);
  __syncthreads();

  // P5: bwd2 ; P6: bwd1 (fp8)
  gemm_bwd_f8(sm.dpA, P + OB_P2B, sm.act2, sm.dpB, wave, lane);
  __syncthreads();
  gemm_bwd_f8(sm.dpB, P + OB_P1B, sm.act1, sm.dpA, wave, lane);
  __syncthreads();

  // P7: bwd0 on waves 0-7 (z = acc/4096); waves 8-15 next-step PRNG
  if (wave < 8) {
    const uint8_t* Pm = P + OB_P0B;
    long bfr[8], afr[8];
#pragma unroll
    for (int kt = 0; kt < 8; ++kt)
      bfr[kt] = *reinterpret_cast<const long*>(Pm + (kt * 128 + c) * 32 + g * 8);
#pragma unroll
    for (int kt = 0; kt < 8; ++kt)
      afr[kt] = *reinterpret_cast<const long*>(&sm.dpA[row16][kt * 32 + g * 8]);
    f32x4 acc = {0.f, 0.f, 0.f, 0.f};
#pragma unroll
    for (int kt = 0; kt < 8; ++kt)
      acc = __builtin_amdgcn_mfma_f32_16x16x32_fp8_fp8(afr[kt], bfr[kt], acc, 0, 0, 0);
    if (c < H_DIM) {
#pragma unroll
      for (int reg = 0; reg < 4; ++reg)
        sm.z_s[(g * 4 + reg) * H_DIM + c] = acc[reg] * INV_ZS;
    }
  } else if (next_s >= 0) {
    const uint32_t ka = sm.keyA[next_s], kb = sm.keyB[next_s];
#pragma unroll
    for (int rr = 0; rr < 2; ++rr) {
      const int r = (wave - 8) * 2 + rr;
#pragma unroll
      for (int itn = 0; itn < 2; ++itn) {
        const int h = lane + itn * 64;
        if (h < H_DIM) {
          const uint32_t f = (uint32_t)(blk * (ROWS * H_DIM) + r * H_DIM + h);
          uint32_t o0, o1;
          threefry2x32(ka, kb, 0u, f, o0, o1);
          const uint32_t bits = o0 ^ o1;
          const float fr = __uint_as_float((bits >> 9) | 0x3F800000u) - 1.0f;
          const float minv = -0.99999994f;  // nextafter(-1, 0)
          const float u = fmaxf(fr * 2.0f + minv, minv);
          const float n = 1.41421354f * erfinv_f32(u);
          sm.dw_s[r * H_DIM + h] = n * sqdt;
        }
      }
    }
  }
  __syncthreads();
}

// ---------------- main kernel ----------------
__global__ __launch_bounds__(THREADS, 4) void fbsde_kernel(
    const float* __restrict__ x0, const float* __restrict__ t0p,
    const float* __restrict__ dtp,
    const float* __restrict__ b0, const float* __restrict__ b1,
    const float* __restrict__ b2, const float* __restrict__ b3,
    const float* __restrict__ W4, const float* __restrict__ b4,
    const uint8_t* __restrict__ P, float* __restrict__ out) {
  __shared__ __align__(16) SmemT sm;

  const int tid = threadIdx.x;
  const int wave = tid >> 6, lane = tid & 63;
  const int blk = blockIdx.x;
  const int row0 = blk * ROWS;

  // ---- init ----
  if (tid < T_STEPS) {
    const uint32_t* K = (const uint32_t*)(P + OB_KEYS);
    sm.keyA[tid] = K[2 * tid];
    sm.keyB[tid] = K[2 * tid + 1];
  }
  for (int e = tid; e < ROWS * H_DIM; e += THREADS)
    sm.x_s[e] = x0[row0 * H_DIM + e];
  for (int e = tid; e < ROWS * 136; e += THREADS) {
    const int r = e / 136, cc = e - r * 136;
    uint16_t v = 0;
    if (cc >= 1 && cc <= H_DIM) v = f2bf(x0[(row0 + r) * H_DIM + cc - 1]);
    sm.actI[r][cc] = v;   // cc==0 -> t=0.0 -> bf16 0
  }
  const float t0v = t0p[0];
  const float dtv = dtp[0];
  const float sqdt = sqrtf(dtv);
  __syncthreads();

  float* const out_xfin = out;                                  // (B,H)
  float* const out_yfin = out + 409600;                         // (B,1)
  float* const out_zfin = out + 413696;                         // (B,H)
  float* const out_xs   = out + 823296;                         // (T,B,H)
  float* const out_yt   = out + 823296 + 40960000;              // (T,B,1)
  float* const out_ys   = out + 823296 + 40960000 + 409600;     // (T,B,1)

  // initial eval at t=0 (no ys write; waves 8-15 generate dW for step 0)
  mlp_eval(sm, P, b0, b1, b2, b3, W4, b4, nullptr, row0, 0, blk, sqdt);

  for (int s = 0; s < T_STEPS; ++s) {
    // ---- SDE phase: y_tilde + x-update + next actI; wave w owns row w ----
    const float tv = t0v + (float)(s + 1) * dtv;
    {
      const int base = wave * H_DIM;
      const int h0 = lane;                 // < 100 always (lane<64)
      const int h1 = lane + 64;            // valid if < 100
      const float xv0 = sm.x_s[base + h0];
      const float zv0 = sm.z_s[base + h0];
      const float dw0 = sm.dw_s[base + h0];
      float s1 = xv0 * zv0;
      float s2 = zv0 * (0.4f * xv0) * dw0;
      float xv1 = 0.f, dw1 = 0.f;
      if (h1 < H_DIM) {
        xv1 = sm.x_s[base + h1];
        const float zv1 = sm.z_s[base + h1];
        dw1 = sm.dw_s[base + h1];
        s1 += xv1 * zv1;
        s2 += zv1 * (0.4f * xv1) * dw1;
      }
#pragma unroll
      for (int off = 32; off >= 1; off >>= 1) {
        s1 += __shfl_xor(s1, off, 64);
        s2 += __shfl_xor(s2, off, 64);
      }
      if (lane == 0) {
        const float yv = sm.y_s[wave];
        const float phi = 0.05f * (yv - s1);
        out_yt[(size_t)s * B_TRAJ + row0 + wave] = yv + phi * dtv + s2;
        sm.actI[wave][0] = f2bf(tv);
      }
      {
        const float x1 = xv0 + (0.4f * xv0) * dw0;
        sm.x_s[base + h0] = x1;
        sm.actI[wave][1 + h0] = f2bf(x1);
        out_xs[(size_t)s * (B_TRAJ * H_DIM) + (size_t)(row0 + wave) * H_DIM + h0] = x1;
        if (h1 < H_DIM) {
          const float x1b = xv1 + (0.4f * xv1) * dw1;
          sm.x_s[base + h1] = x1b;
          sm.actI[wave][1 + h1] = f2bf(x1b);
          out_xs[(size_t)s * (B_TRAJ * H_DIM) + (size_t)(row0 + wave) * H_DIM + h1] = x1b;
        }
      }
    }
    __syncthreads();

    mlp_eval(sm, P, b0, b1, b2, b3, W4, b4, out_ys + (size_t)s * B_TRAJ,
             row0, (s + 1 < T_STEPS) ? s + 1 : -1, blk, sqdt);
  }

  for (int e = tid; e < ROWS * H_DIM; e += THREADS) {
    out_xfin[(size_t)row0 * H_DIM + e] = sm.x_s[e];
    out_zfin[(size_t)row0 * H_DIM + e] = sm.z_s[e];
  }
  if (tid < ROWS) out_yfin[row0 + tid] = sm.y_s[tid];
}

extern "C" void kernel_launch(void* const* d_in, const int* in_sizes, int n_in,
                              void* d_out, int out_size, void* d_ws, size_t ws_size,
                              hipStream_t stream) {
  (void)in_sizes; (void)n_in; (void)ws_size; (void)out_size;
  const float* x0 = (const float*)d_in[0];
  const float* t0 = (const float*)d_in[1];
  const float* dt = (const float*)d_in[2];
  const float* W0 = (const float*)d_in[4];
  const float* b0 = (const float*)d_in[5];
  const float* W1 = (const float*)d_in[6];
  const float* b1 = (const float*)d_in[7];
  const float* W2 = (const float*)d_in[8];
  const float* b2 = (const float*)d_in[9];
  const float* W3 = (const float*)d_in[10];
  const float* b3 = (const float*)d_in[11];
  const float* W4 = (const float*)d_in[12];
  const float* b4 = (const float*)d_in[13];
  uint8_t* P = (uint8_t*)d_ws;
  float* out = (float*)d_out;

  hipLaunchKernelGGL(pack_kernel, dim3(PACK_GRID), dim3(256), 0, stream,
                     W0, W1, W2, W3, W4, P);
  hipLaunchKernelGGL(fbsde_kernel, dim3(NBLK), dim3(THREADS), 0, stream,
                     x0, t0, dt, b0, b1, b2, b3, W4, b4, P, out);
}